// Round 11
// baseline (2830.541 us; speedup 1.0000x reference)
//
#include <hip/hip_runtime.h>
#include <hip/hip_bf16.h>

// ---------------------------------------------------------------------------
// Round 17: deepen the register ring 4->8 + slice-inner loops.
//   R16 proved the asm register ring holds at 512-thr blocks (VGPR=128, no
//   spill) but 4 slots only cover ~200cy of loaded-L2 latency -> 310cy/chunk.
//   At 1 block/CU (pad-pinned) x 512thr = 2 waves/SIMD the VGPR budget is
//   256; spend it: 8-slot ring (64 VGPRs, strict vmcnt(7), 96%8=0 so slots
//   are step-invariant) + slice-inner loops (one hc fragment read feeds both
//   slices' MFMAs: fragment reads 48->24 b128/thread/step, aH[2][4]).
//   Everything outside k_encoder unchanged from R16.
// ---------------------------------------------------------------------------

typedef unsigned short ushort_t;
using short4v = __attribute__((ext_vector_type(4))) short;   // 4 x bf16
using short8  = __attribute__((ext_vector_type(8))) short;   // 8 x bf16
using floatx4 = __attribute__((ext_vector_type(4))) float;   // MFMA accumulator

#define DEVFN static __device__ __forceinline__

DEVFN float bs2f(ushort_t u) {
    union { float f; unsigned v; } c; c.v = ((unsigned)u) << 16; return c.f;
}
DEVFN ushort_t f2bs(float f) {
    __hip_bfloat16 h = __float2bfloat16(f);
    return *reinterpret_cast<ushort_t*>(&h);
}
DEVFN float gload(const void* p, long i, int bf) {
    if (bf) return bs2f(((const ushort_t*)p)[i]);
    return ((const float*)p)[i];
}
DEVFN float sigm(float x) { return 1.f / (1.f + __expf(-x)); }
DEVFN float ftanh(float x) {
    float t = __expf(-2.f * fabsf(x));
    float r = (1.f - t) / (1.f + t);
    return copysignf(r, x);
}
DEVFN short8 ld8(const ushort_t* p) { return *reinterpret_cast<const short8*>(p); }

// publish LDS writes + barrier WITHOUT draining vmcnt (ring loads stay live)
DEVFN void bar_lgkm() {
    asm volatile("s_waitcnt lgkmcnt(0)" ::: "memory");
    __builtin_amdgcn_s_barrier();
}

// ring refill: in-place register redefine. "+v" ties the new load to the same
// physical regs (no SSA balloon) and orders it after the consuming MFMA.
#define GLD16R(dst, src) \
    asm volatile("global_load_dwordx4 %0, %1, off" : "+v"(dst) : "v"(src))

// strict ring wait: at consume of seq j exactly 7 ring refills are younger;
// foreign plain VMEM only makes the wait stricter (in-order retirement).
// sched_barrier(0x3F7) = everything-but-MFMA may cross: pins the consuming
// MFMA below the wait (rule #18) without constraining DS/VALU scheduling.
#define VW7() do { asm volatile("s_waitcnt vmcnt(7)"); \
                   __builtin_amdgcn_sched_barrier(0x3F7); } while (0)

struct SrcPtrs { const void* p[26]; };
struct WsPtrs {
    // wes/whh hold PERMUTED (fragment-major) data; wih holds PLAIN bf16
    // row-major Wih_e (GEMM input).
    ushort_t *wcfg, *bcfg, *eh, *ew, *es, *wis, *bis, *wes, *vds, *bvds,
             *whh, *wih, *bih, *bhh, *wdt, *bdt, *wd2t, *vdt, *bvdt,
             *wihd, *whhd, *bihd, *bhhd;
};

// ---------------------------------------------------------------------------
__global__ void k_detect(const void* probe, int* flag) {
    if (threadIdx.x == 0 && blockIdx.x == 0) {
        const ushort_t* u = (const ushort_t*)probe;
        int ok = 1;
        for (int i = 0; i < 16; ++i) {
            ushort_t v = u[2 * i];
            int e = (v >> 7) & 0xFF;
            if (!(v == 0 || (e >= 96 && e <= 126))) ok = 0;
        }
        *flag = ok;
    }
}

// ---------------------------------------------------------------------------
// k_cvt: small tensors only (wes/whh/wih are handled by the perm kernels).
// ---------------------------------------------------------------------------
__global__ __launch_bounds__(256) void k_cvt(SrcPtrs sp, WsPtrs wp, const int* flagp) {
    int bf = *flagp;
    const void* src = nullptr; ushort_t* dst = nullptr; long n = 0;
    switch (blockIdx.x) {
        case 0:  src = sp.p[3];  dst = wp.wcfg; n = 320;    break;
        case 1:  src = sp.p[4];  dst = wp.bcfg; n = 10;     break;
        case 2:  src = sp.p[5];  dst = wp.eh;   n = 120;    break;
        case 3:  src = sp.p[6];  dst = wp.ew;   n = 24;     break;
        case 4:  src = sp.p[7];  dst = wp.es;   n = 15;     break;
        case 5:  src = sp.p[16]; dst = wp.wis;  n = 65536;  break;
        case 6:  src = sp.p[17]; dst = wp.bis;  n = 256;    break;
        case 8:  src = sp.p[19]; dst = wp.vds;  n = 256;    break;
        case 9:  src = sp.p[20]; dst = wp.bvds; n = 1;      break;
        case 12: src = sp.p[10]; dst = wp.bih;  n = 1024;   break;
        case 13: src = sp.p[11]; dst = wp.bhh;  n = 1024;   break;
        case 14: src = sp.p[21]; dst = wp.wdt;  n = 65536;  break;
        case 15: src = sp.p[22]; dst = wp.bdt;  n = 256;    break;
        case 16: src = sp.p[23]; dst = wp.wd2t; n = 512;    break;
        case 17: src = sp.p[24]; dst = wp.vdt;  n = 256;    break;
        case 18: src = sp.p[25]; dst = wp.bvdt; n = 1;      break;
        case 19: src = sp.p[12]; dst = wp.wihd; n = 1028;   break;
        case 20: src = sp.p[13]; dst = wp.whhd; n = 4;      break;
        case 21: src = sp.p[14]; dst = wp.bihd; n = 4;      break;
        case 22: src = sp.p[15]; dst = wp.bhhd; n = 4;      break;
        default: return;
    }
    for (long i = threadIdx.x; i < n; i += 256) {
        float v = bf ? bs2f(((const ushort_t*)src)[i]) : ((const float*)src)[i];
        dst[i] = f2bs(v);
    }
}

// ---------------------------------------------------------------------------
// k_permA: y=0: Whh (1024x256 row-major) -> fragment-major (encoder layout).
//          y=1: Wih -> PLAIN bf16 copy (row-major; consumed by the AX GEMM).
// ---------------------------------------------------------------------------
__global__ __launch_bounds__(256) void k_permA(
    const void* whh_src, const void* wih_src,
    ushort_t* whhp, ushort_t* wihb, const int* flagp)
{
    int bf = *flagp;
    long base = (long)blockIdx.x * 2048;
    if (blockIdx.y == 1) {
#pragma unroll
        for (int ii = 0; ii < 8; ++ii) {
            long p = base + threadIdx.x + ii * 256;
            wihb[p] = f2bs(gload(wih_src, p, bf));
        }
        return;
    }
#pragma unroll
    for (int ii = 0; ii < 8; ++ii) {
        long p = base + threadIdx.x + ii * 256;
        int c = (int)(p >> 9), l = (int)((p >> 3) & 63), e = (int)(p & 7);
        int w = c >> 5, kk = (c >> 2) & 7, g = c & 3;
        int q = l >> 4, ln = l & 15;
        long si = (long)(g * 256 + w * 16 + ln) * 256 + kk * 32 + q * 8 + e;
        whhp[p] = f2bs(gload(whh_src, si, bf));
    }
}

// ---------------------------------------------------------------------------
// k_permB: Wes (256x512 row-major) -> fragment-major. c = w*16 + kk (kk 0..15).
// ---------------------------------------------------------------------------
__global__ __launch_bounds__(256) void k_permB(
    const void* wes_src, ushort_t* wesp, const int* flagp)
{
    int bf = *flagp;
    long base = (long)blockIdx.x * 2048;
#pragma unroll
    for (int ii = 0; ii < 8; ++ii) {
        long p = base + threadIdx.x + ii * 256;
        int c = (int)(p >> 9), l = (int)((p >> 3) & 63), e = (int)(p & 7);
        int w = c >> 4, kk = c & 15;
        int q = l >> 4, ln = l & 15;
        long si = (long)(w * 16 + ln) * 512 + kk * 32 + q * 8 + e;
        wesp[p] = f2bs(gload(wes_src, si, bf));
    }
}

// ---------------------------------------------------------------------------
// k_build: features. 24576 blocks x 256 thr, 4 rows/block.
// ---------------------------------------------------------------------------
__global__ __launch_bounds__(256) void k_build(
    const void* __restrict__ pq, const void* __restrict__ cfg_in,
    const int* __restrict__ timei, WsPtrs wp, const int* __restrict__ flagp,
    ushort_t* __restrict__ inputs)
{
    int bf = *flagp;
    int ch = threadIdx.x;
    for (int rr = 0; rr < 4; ++rr) {
        long row = (long)blockIdx.x * 4 + rr;
        float v;
        if (ch < 235) {
            v = gload(pq, row * 235 + ch, bf);
        } else if (ch < 245) {
            int j = ch - 235;
            float acc = bs2f(wp.bcfg[j]);
            for (int k = 0; k < 32; ++k)
                acc += gload(cfg_in, row * 32 + k, bf) * bs2f(wp.wcfg[j * 32 + k]);
            v = acc;
        } else if (ch < 250) {
            v = bs2f(wp.eh[timei[row * 3 + 0] * 5 + (ch - 245)]);
        } else if (ch < 253) {
            v = bs2f(wp.ew[timei[row * 3 + 1] * 3 + (ch - 250)]);
        } else {
            v = bs2f(wp.es[timei[row * 3 + 2] * 3 + (ch - 253)]);
        }
        inputs[row * 256 + ch] = f2bs(v);
    }
}

// ---------------------------------------------------------------------------
// k_gemm: out = A @ W.T (+ bias). A:(98304x256), W row-major ws bf16, K=256.
// 128x128 tiles, BK=32, 4 waves of 64x64.
// ---------------------------------------------------------------------------
__global__ __launch_bounds__(256) void k_gemm(
    const ushort_t* __restrict__ A, const ushort_t* __restrict__ W,
    const ushort_t* __restrict__ bias, ushort_t* __restrict__ out,
    int ostride, int gatherB)
{
    const int K = 256;
    __shared__ alignas(16) ushort_t At[128][40];
    __shared__ alignas(16) ushort_t Bt[128][40];

    int tid  = threadIdx.x;
    int lane = tid & 63, wave = tid >> 6;
    int wm = wave >> 1, wn = wave & 1;
    int q = lane >> 4, ln = lane & 15;
    long mbase = (long)blockIdx.x * 128;

    floatx4 acc[4][4];
#pragma unroll
    for (int i = 0; i < 4; ++i)
#pragma unroll
        for (int j = 0; j < 4; ++j) acc[i][j] = (floatx4){0.f, 0.f, 0.f, 0.f};

    for (int k0 = 0; k0 < K; k0 += 32) {
        __syncthreads();
#pragma unroll
        for (int it = 0; it < 2; ++it) {
            int c = tid + it * 256;
            int r = c >> 2, kc = (c & 3) * 8;
            int wrow = gatherB ? (((r & 3) << 8) + ((int)blockIdx.y << 5) + (r >> 2))
                               : ((int)blockIdx.y * 128 + r);
            *reinterpret_cast<short8*>(&At[r][kc]) = ld8(&A[(mbase + r) * K + k0 + kc]);
            *reinterpret_cast<short8*>(&Bt[r][kc]) = ld8(&W[(long)wrow * K + k0 + kc]);
        }
        __syncthreads();
        short8 af[4];
#pragma unroll
        for (int mt = 0; mt < 4; ++mt)
            af[mt] = *reinterpret_cast<const short8*>(&At[wm * 64 + mt * 16 + ln][q * 8]);
#pragma unroll
        for (int nt = 0; nt < 4; ++nt) {
            short8 bf = *reinterpret_cast<const short8*>(&Bt[wn * 64 + nt * 16 + ln][q * 8]);
#pragma unroll
            for (int mt = 0; mt < 4; ++mt)
                acc[mt][nt] = __builtin_amdgcn_mfma_f32_16x16x32_bf16(af[mt], bf, acc[mt][nt], 0, 0, 0);
        }
    }

#pragma unroll
    for (int mt = 0; mt < 4; ++mt)
#pragma unroll
        for (int nt = 0; nt < 4; ++nt)
#pragma unroll
            for (int reg = 0; reg < 4; ++reg) {
                long row = mbase + wm * 64 + mt * 16 + q * 4 + reg;
                int  col = (int)blockIdx.y * 128 + wn * 64 + nt * 16 + ln;
                float bv = bias ? bs2f(bias[col]) : 0.f;
                out[row * (long)ostride + col] = f2bs(acc[mt][nt][reg] + bv);
            }
}

// ---------------------------------------------------------------------------
// k_encoder: 64 blocks x 512 thr (8 waves), 16 rows/block, 1 block/CU.
// Wave w owns cols [w*32, w*32+32) as two 16-col slices s=0,1 (wprime=2w+s).
// Weight stream per wave per step: 96 x 1KB chunks, seq j in [0,96):
//   j<32 : s=j&1, c=j>>1        -> wes[s] chunk c
//   j>=32: jj=j-32; s=jj&1      -> whh[s] chunk jj>>1
// 8-slot REGISTER ring Wr[8] (64 VGPRs), slot = j&7 (96%8==0: invariant),
// refilled by asm global_load_dwordx4 ("+v"), strict vmcnt(7)+sched_barrier;
// refills cross barriers and the step boundary. Slice-INNER loops: one hc
// fragment read feeds both slices (24 b128/thread/step total).
// Schedule: mid(t-1)|ax/wi| attn c=0..15 x s +epi | barA |
//           aval | gates kk,g x s | cell | barC
// ---------------------------------------------------------------------------
#define MFMA16(a, b, c) __builtin_amdgcn_mfma_f32_16x16x32_bf16((a), (b), (c), 0, 0, 0)

__global__ __launch_bounds__(512) void k_encoder(
    const ushort_t* __restrict__ wi, const ushort_t* __restrict__ ax,
    WsPtrs wp, ushort_t* __restrict__ mid)
{
    __shared__ alignas(16) ushort_t hcb[2][16][520];   // 33 KB [h|c] dbuf
    __shared__ alignas(16) float aPartT[16][20];       // [wprime][row]
    __shared__ ushort_t occupancy_pad[30720];          // 60 KB: 1 block/CU

    int tid  = threadIdx.x;
    int lane = tid & 63, w = tid >> 6;                 // w in [0,8)
    int q = lane >> 4, ln = lane & 15;
    long row0 = (long)blockIdx.x * 16;
    int u0 = w * 32 + ln;

    for (int i = tid; i < 2 * 16 * 520; i += 512) ((ushort_t*)hcb)[i] = 0;

    float bc[2][4], vds[2];
#pragma unroll
    for (int s = 0; s < 2; ++s) {
        int us = u0 + s * 16;
        bc[s][0] = bs2f(wp.bih[us])       + bs2f(wp.bhh[us]);
        bc[s][1] = bs2f(wp.bih[256 + us]) + bs2f(wp.bhh[256 + us]);
        bc[s][2] = bs2f(wp.bih[512 + us]) + bs2f(wp.bhh[512 + us]);
        bc[s][3] = bs2f(wp.bih[768 + us]) + bs2f(wp.bhh[768 + us]);
        vds[s]   = bs2f(wp.vds[us]);
    }
    float bVd = bs2f(wp.bvds[0]);

    const ushort_t* wesW0 = wp.wes + ((long)(2 * w)     << 13) + lane * 8;
    const ushort_t* wesW1 = wp.wes + ((long)(2 * w + 1) << 13) + lane * 8;
    const ushort_t* whhW0 = wp.whh + ((long)(2 * w)     << 14) + lane * 8;
    const ushort_t* whhW1 = wp.whh + ((long)(2 * w + 1) << 14) + lane * 8;

    // single base pointers (per-reg offsets recomputed; saves VGPRs)
    const ushort_t* wiB0 = wi + ((row0 + q * 4) * 96) * 256 + u0;
    const ushort_t* axB0 = ax + ((row0 + q * 4) * 96) * 1024 + u0 * 4;

    int mr = tid >> 5, mc = (tid & 31) * 8;            // mid-writer: 16B each
    ushort_t* midB = mid + (row0 + mr) * 96 * 256 + mc;

    // keep the pad alive (branch never taken: gridDim.x == 64)
    if (blockIdx.x > 60000) {
        occupancy_pad[tid] = (ushort_t)tid;
        midB[0] = occupancy_pad[(tid + 1) & 511];
    }

    float creg[2][4] = {{0.f, 0.f, 0.f, 0.f}, {0.f, 0.f, 0.f, 0.f}};
    __syncthreads();

    // seq j -> global chunk address (compile-time resolved: j is unrolled)
    auto sp3 = [&](int j) -> const ushort_t* {
        if (j < 32) {
            int s = j & 1, c = j >> 1;
            return (s ? wesW1 : wesW0) + (c << 9);
        }
        int jj = j - 32, s = jj & 1, c = jj >> 1;
        return (s ? whhW1 : whhW0) + (c << 9);
    };

    // ---- ring prologue: seqs 0..7 in flight
    short8 Wr[8] = {};
#pragma unroll
    for (int j = 0; j < 8; ++j) GLD16R(Wr[j], sp3(j));

    for (int t = 0; t < 96; ++t) {
        ushort_t (*R)[520]  = hcb[t & 1];
        ushort_t (*Wb)[520] = hcb[(t & 1) ^ 1];

        // ---- coalesced mid write for step t-1 (t=0: dummy to slot 95)
        {
            long toff = (long)(t > 0 ? t - 1 : 95) * 256;
            uint4 hv = *reinterpret_cast<const uint4*>(&R[mr][mc]);
            *reinterpret_cast<uint4*>(midB + toff) = hv;
        }
        // ---- ax (2x4x8B) + wi (2x4x2B) prefetch (plain; compiler-scheduled)
        short4v axv[2][4]; float wiv[2][4];
#pragma unroll
        for (int reg = 0; reg < 4; ++reg) {
            const ushort_t* a0 = axB0 + ((long)reg * 96 + t) * 1024;
            axv[0][reg] = *reinterpret_cast<const short4v*>(a0);
            axv[1][reg] = *reinterpret_cast<const short4v*>(a0 + 64);
            const ushort_t* w0 = wiB0 + ((long)reg * 96 + t) * 256;
            wiv[0][reg] = bs2f(w0[0]);
            wiv[1][reg] = bs2f(w0[16]);
        }

        // ---- attn matvec: K=512 over [h|c]; one fragment feeds both slices
        floatx4 acc1[2];
        acc1[0] = (floatx4){0.f, 0.f, 0.f, 0.f};
        acc1[1] = (floatx4){0.f, 0.f, 0.f, 0.f};
#pragma unroll
        for (int c = 0; c < 16; ++c) {
            short8 af = ld8(&R[ln][c * 32 + q * 8]);
#pragma unroll
            for (int s = 0; s < 2; ++s) {
                const int j = c * 2 + s;
                VW7();
                acc1[s] = MFMA16(af, Wr[j & 7], acc1[s]);
                GLD16R(Wr[j & 7], sp3((j + 8) % 96));
            }
        }

        // ---- attn epilogue: tanh, scale, reduce over 16 ln lanes
        float p4[2][4];
#pragma unroll
        for (int s = 0; s < 2; ++s)
#pragma unroll
            for (int reg = 0; reg < 4; ++reg)
                p4[s][reg] = ftanh(acc1[s][reg] + wiv[s][reg]) * vds[s];
#pragma unroll
        for (int m = 1; m < 16; m <<= 1) {
#pragma unroll
            for (int s = 0; s < 2; ++s)
#pragma unroll
                for (int reg = 0; reg < 4; ++reg)
                    p4[s][reg] += __shfl_xor(p4[s][reg], m, 64);
        }
        if (ln == 0) {
#pragma unroll
            for (int s = 0; s < 2; ++s) {
                floatx4 pv = {p4[s][0], p4[s][1], p4[s][2], p4[s][3]};
                *reinterpret_cast<floatx4*>(&aPartT[2 * w + s][q * 4]) = pv;
            }
        }
        bar_lgkm();   // barrier A: aPartT visible (ring loads stay live)

        // ---- aval: per-row sum of 16 wprime partials (broadcast b128 reads)
        floatx4 av = {bVd, bVd, bVd, bVd};
#pragma unroll
        for (int ww = 0; ww < 16; ++ww)
            av += *reinterpret_cast<const floatx4*>(&aPartT[ww][q * 4]);

        // ---- gates: aH = h@Whh.T; one fragment feeds 8 MFMAs (4 gates x 2 s)
        floatx4 aH[2][4];
#pragma unroll
        for (int s = 0; s < 2; ++s)
#pragma unroll
            for (int g = 0; g < 4; ++g) aH[s][g] = (floatx4){0.f, 0.f, 0.f, 0.f};
#pragma unroll
        for (int kk = 0; kk < 8; ++kk) {
            short8 af = ld8(&R[ln][kk * 32 + q * 8]);
#pragma unroll
            for (int g = 0; g < 4; ++g) {
#pragma unroll
                for (int s = 0; s < 2; ++s) {
                    const int j = 32 + (kk * 4 + g) * 2 + s;
                    VW7();
                    aH[s][g] = MFMA16(af, Wr[j & 7], aH[s][g]);
                    GLD16R(Wr[j & 7], sp3((j + 8) % 96));   // wraps to next step
                }
            }
        }

        // ---- cell update: rows q*4+reg, cols u0 and u0+16; write into Wb
#pragma unroll
        for (int s = 0; s < 2; ++s) {
            int us = u0 + s * 16;
#pragma unroll
            for (int reg = 0; reg < 4; ++reg) {
                float a  = av[reg];
                float gi = aH[s][0][reg] + a * bs2f((ushort_t)axv[s][reg][0]) + bc[s][0];
                float gf = aH[s][1][reg] + a * bs2f((ushort_t)axv[s][reg][1]) + bc[s][1];
                float gg = aH[s][2][reg] + a * bs2f((ushort_t)axv[s][reg][2]) + bc[s][2];
                float go = aH[s][3][reg] + a * bs2f((ushort_t)axv[s][reg][3]) + bc[s][3];
                float c2 = sigm(gf) * creg[s][reg] + sigm(gi) * ftanh(gg);
                float h2 = sigm(go) * ftanh(c2);
                creg[s][reg] = c2;
                int r = q * 4 + reg;
                Wb[r][us] = f2bs(h2);
                Wb[r][256 + us] = f2bs(c2);
            }
        }
        bar_lgkm();   // barrier C: new state published
    }

    // retire dangling ring loads, then the real final mid write (h_96)
    asm volatile("s_waitcnt vmcnt(0)" ::: "memory");
    {
        uint4 hv = *reinterpret_cast<const uint4*>(&hcb[0][mr][mc]);
        *reinterpret_cast<uint4*>(midB + 95L * 256) = hv;
    }
}

// ---------------------------------------------------------------------------
// k_decoder: 1024 blocks (one batch row), 256 thr, 16 sequential steps.
// ---------------------------------------------------------------------------
__global__ __launch_bounds__(256) void k_decoder(
    const ushort_t* __restrict__ mid, const ushort_t* __restrict__ wd,
    WsPtrs wp, const int* __restrict__ flagp, void* __restrict__ out)
{
    __shared__ ushort_t wdl[96][264];
    __shared__ float qL[256], aLs[96], ctxL[256], VdtL[256], gL[4];
    __shared__ float st[3];

    int tid = threadIdx.x;
    long b = blockIdx.x;
    int bf = *flagp;

    for (int c = tid; c < 96 * 256; c += 256) {
        int tp = c >> 8, chn = c & 255;
        wdl[tp][chn] = wd[(b * 96 + tp) * 256 + chn];
    }
    qL[tid] = 0.f; ctxL[tid] = 0.f;
    if (tid < 96) aLs[tid] = 0.f;
    if (tid < 4)  gL[tid] = 0.f;
    VdtL[tid] = bs2f(wp.vdt[tid]);
    if (tid == 0) {
        st[0] = 0.f; st[1] = 0.f;
        st[2] = bs2f(mid[(b * 96 + 95) * 256 + 2]);
    }
    float bVdt = bs2f(wp.bvdt[0]);
    float w2a = bs2f(wp.wd2t[tid * 2]), w2b = bs2f(wp.wd2t[tid * 2 + 1]);
    __syncthreads();

    for (int s = 0; s < 16; ++s) {
        float hi = st[0], ci = st[1], prev = st[2];
        qL[tid] = hi * w2a + ci * w2b;
        __syncthreads();
        {   // attn scores: wave v, lanes split the 256-dot
            int v = tid >> 6, l = tid & 63;
            for (int tp = v; tp < 96; tp += 4) {
                float sacc = 0.f;
#pragma unroll
                for (int e = 0; e < 4; ++e) {
                    int u = l * 4 + e;
                    sacc += ftanh(qL[u] + bs2f(wdl[tp][u])) * VdtL[u];
                }
#pragma unroll
                for (int m = 1; m < 64; m <<= 1) sacc += __shfl_xor(sacc, m, 64);
                if (l == 0) aLs[tp] = sacc + bVdt;
            }
        }
        __syncthreads();
        {
            float acc = 0.f;
            for (int tp = 0; tp < 96; ++tp)
                acc += aLs[tp] * bs2f(mid[(b * 96 + tp) * 256 + tid]);
            ctxL[tid] = acc;
        }
        __syncthreads();
        {   // gates: wave g computes gate g; lanes split the ctx-dot
            int g = tid >> 6, k = tid & 63;
            float part = 0.f;
#pragma unroll
            for (int e = 0; e < 4; ++e) {
                int u = k + e * 64;
                part += bs2f(wp.wihd[g * 257 + u]) * ctxL[u];
            }
#pragma unroll
            for (int m = 1; m < 64; m <<= 1) part += __shfl_xor(part, m, 64);
            if (k == 0)
                gL[g] = part + bs2f(wp.bihd[g]) + bs2f(wp.bhhd[g])
                      + bs2f(wp.whhd[g]) * hi + bs2f(wp.wihd[g * 257 + 256]) * prev;
        }
        __syncthreads();
        if (tid == 0) {
            float c2 = sigm(gL[1]) * ci + sigm(gL[0]) * ftanh(gL[2]);
            float h2 = sigm(gL[3]) * ftanh(c2);
            st[0] = h2; st[1] = c2; st[2] = h2;
            long oi = b * 16 + s;
            if (bf) ((ushort_t*)out)[oi] = f2bs(h2);
            else    ((float*)out)[oi] = h2;
        }
        __syncthreads();
    }
}

// ---------------------------------------------------------------------------
extern "C" void kernel_launch(void* const* d_in, const int* in_sizes, int n_in,
                              void* d_out, int out_size, void* d_ws, size_t ws_size,
                              hipStream_t stream)
{
    const long MT = 1024L * 96;   // 98304 rows

    int* flagp = (int*)d_ws;
    ushort_t* base = (ushort_t*)((char*)d_ws + 256);

    SrcPtrs sp;
    for (int i = 0; i < 26; ++i) sp.p[i] = d_in[i];

    static const long sizes[23] = {
        320, 10, 120, 24, 15, 65536, 256, 131072, 256, 1,
        262144, 262144, 1024, 1024, 65536, 256, 512, 256, 1,
        1028, 4, 4, 4
    };
    ushort_t* ptrs[23];
    long off = 0;
    for (int i = 0; i < 23; ++i) {
        ptrs[i] = base + off;
        off += (sizes[i] + 7) & ~7L;   // 16B-aligned layout
    }

    WsPtrs wp;
    wp.wcfg = ptrs[0];  wp.bcfg = ptrs[1];  wp.eh   = ptrs[2];  wp.ew   = ptrs[3];
    wp.es   = ptrs[4];  wp.wis  = ptrs[5];  wp.bis  = ptrs[6];  wp.wes  = ptrs[7];
    wp.vds  = ptrs[8];  wp.bvds = ptrs[9];  wp.whh  = ptrs[10]; wp.wih  = ptrs[11];
    wp.bih  = ptrs[12]; wp.bhh  = ptrs[13]; wp.wdt  = ptrs[14]; wp.bdt  = ptrs[15];
    wp.wd2t = ptrs[16]; wp.vdt  = ptrs[17]; wp.bvdt = ptrs[18]; wp.wihd = ptrs[19];
    wp.whhd = ptrs[20]; wp.bihd = ptrs[21]; wp.bhhd = ptrs[22];

    ushort_t* inputs = base + off;            // MT*256
    ushort_t* wib    = inputs + MT * 256;     // MT*256
    ushort_t* midb   = wib + MT * 256;        // MT*256
    ushort_t* axb    = midb + MT * 256;       // MT*1024 (201 MB): AX = x@Wih.T
    ushort_t* wdb    = wib;                   // alias: wi dead after encoder

    k_detect<<<1, 64, 0, stream>>>(d_in[3], flagp);
    k_cvt<<<23, 256, 0, stream>>>(sp, wp, flagp);
    k_permA<<<dim3(128, 2), 256, 0, stream>>>(d_in[9], d_in[8], wp.whh, wp.wih, flagp);
    k_permB<<<64, 256, 0, stream>>>(d_in[18], wp.wes, flagp);
    k_build<<<24576, 256, 0, stream>>>(d_in[0], d_in[1], (const int*)d_in[2],
                                       wp, flagp, inputs);
    k_gemm<<<dim3(768, 2), 256, 0, stream>>>(inputs, wp.wis, wp.bis, wib, 256, 0);
    k_gemm<<<dim3(768, 8), 256, 0, stream>>>(inputs, wp.wih, nullptr, axb, 1024, 1);
    k_encoder<<<64, 512, 0, stream>>>(wib, axb, wp, midb);
    k_gemm<<<dim3(768, 2), 256, 0, stream>>>(midb, wp.wdt, wp.bdt, wdb, 256, 0);
    k_decoder<<<1024, 256, 0, stream>>>(midb, wdb, wp, flagp, d_out);
}

// Round 15
// 2360.115 us; speedup vs baseline: 1.1993x; 1.1993x over previous
//
#include <hip/hip_runtime.h>
#include <hip/hip_bf16.h>

// ---------------------------------------------------------------------------
// Round 19: proven R16 base + (512,2) VGPR unlock + 8-slot register ring.
//   R18/R18b/R18c's cross-step ax/wi prefetch NaN'd twice (suspect: mixed
//   load/store vmcnt FIFO semantics breaking the VW20 count) -> dropped.
//   This round is EXACT R16 (1190us, passed, VGPR=128, no spill) with only:
//   (1) __launch_bounds__(512, 2): request 2 waves/EU -> 256-VGPR budget.
//   (2) ring 4 -> 8 slots (Wr[8], +32 VGPRs -> ~160 total), strict vmcnt(7)
//       (7 ring refills younger at each consume; interleaved plain VMEM only
//       makes the wait stricter -- R16-validated safety argument).
//   96 % 8 == 0 -> slots step-invariant; refills wrap the step boundary.
//   Validation bits: VGPR ~160 & FETCH ~129MB = unlocked; VGPR 128 &
//   FETCH >300MB = denied/spilled (register path ceiling).
// ---------------------------------------------------------------------------

typedef unsigned short ushort_t;
using short4v = __attribute__((ext_vector_type(4))) short;   // 4 x bf16
using short8  = __attribute__((ext_vector_type(8))) short;   // 8 x bf16
using floatx4 = __attribute__((ext_vector_type(4))) float;   // MFMA accumulator

#define DEVFN static __device__ __forceinline__

DEVFN float bs2f(ushort_t u) {
    union { float f; unsigned v; } c; c.v = ((unsigned)u) << 16; return c.f;
}
DEVFN ushort_t f2bs(float f) {
    __hip_bfloat16 h = __float2bfloat16(f);
    return *reinterpret_cast<ushort_t*>(&h);
}
DEVFN float gload(const void* p, long i, int bf) {
    if (bf) return bs2f(((const ushort_t*)p)[i]);
    return ((const float*)p)[i];
}
DEVFN float sigm(float x) { return 1.f / (1.f + __expf(-x)); }
DEVFN float ftanh(float x) {
    float t = __expf(-2.f * fabsf(x));
    float r = (1.f - t) / (1.f + t);
    return copysignf(r, x);
}
DEVFN short8 ld8(const ushort_t* p) { return *reinterpret_cast<const short8*>(p); }

// publish LDS writes + barrier WITHOUT draining vmcnt (ring loads stay live)
DEVFN void bar_lgkm() {
    asm volatile("s_waitcnt lgkmcnt(0)" ::: "memory");
    __builtin_amdgcn_s_barrier();
}

// ring refill: in-place register redefine. "+v" ties the new load to the same
// physical regs (no SSA balloon) and orders it after the consuming MFMA.
#define GLD16R(dst, src) \
    asm volatile("global_load_dwordx4 %0, %1, off" : "+v"(dst) : "v"(src))

// strict ring wait: at consume of seq j exactly 7 ring refills are younger;
// interleaved plain VMEM only makes the wait stricter (in-order retirement).
// sched_barrier(0x3F7) = everything-but-MFMA may cross: pins the consuming
// MFMA below the wait (rule #18) without constraining DS/VALU scheduling.
#define VW7() do { asm volatile("s_waitcnt vmcnt(7)"); \
                   __builtin_amdgcn_sched_barrier(0x3F7); } while (0)

struct SrcPtrs { const void* p[26]; };
struct WsPtrs {
    // wes/whh hold PERMUTED (fragment-major) data; wih holds PLAIN bf16
    // row-major Wih_e (GEMM input).
    ushort_t *wcfg, *bcfg, *eh, *ew, *es, *wis, *bis, *wes, *vds, *bvds,
             *whh, *wih, *bih, *bhh, *wdt, *bdt, *wd2t, *vdt, *bvdt,
             *wihd, *whhd, *bihd, *bhhd;
};

// ---------------------------------------------------------------------------
__global__ void k_detect(const void* probe, int* flag) {
    if (threadIdx.x == 0 && blockIdx.x == 0) {
        const ushort_t* u = (const ushort_t*)probe;
        int ok = 1;
        for (int i = 0; i < 16; ++i) {
            ushort_t v = u[2 * i];
            int e = (v >> 7) & 0xFF;
            if (!(v == 0 || (e >= 96 && e <= 126))) ok = 0;
        }
        *flag = ok;
    }
}

// ---------------------------------------------------------------------------
// k_cvt: small tensors only (wes/whh/wih are handled by the perm kernels).
// ---------------------------------------------------------------------------
__global__ __launch_bounds__(256) void k_cvt(SrcPtrs sp, WsPtrs wp, const int* flagp) {
    int bf = *flagp;
    const void* src = nullptr; ushort_t* dst = nullptr; long n = 0;
    switch (blockIdx.x) {
        case 0:  src = sp.p[3];  dst = wp.wcfg; n = 320;    break;
        case 1:  src = sp.p[4];  dst = wp.bcfg; n = 10;     break;
        case 2:  src = sp.p[5];  dst = wp.eh;   n = 120;    break;
        case 3:  src = sp.p[6];  dst = wp.ew;   n = 24;     break;
        case 4:  src = sp.p[7];  dst = wp.es;   n = 15;     break;
        case 5:  src = sp.p[16]; dst = wp.wis;  n = 65536;  break;
        case 6:  src = sp.p[17]; dst = wp.bis;  n = 256;    break;
        case 8:  src = sp.p[19]; dst = wp.vds;  n = 256;    break;
        case 9:  src = sp.p[20]; dst = wp.bvds; n = 1;      break;
        case 12: src = sp.p[10]; dst = wp.bih;  n = 1024;   break;
        case 13: src = sp.p[11]; dst = wp.bhh;  n = 1024;   break;
        case 14: src = sp.p[21]; dst = wp.wdt;  n = 65536;  break;
        case 15: src = sp.p[22]; dst = wp.bdt;  n = 256;    break;
        case 16: src = sp.p[23]; dst = wp.wd2t; n = 512;    break;
        case 17: src = sp.p[24]; dst = wp.vdt;  n = 256;    break;
        case 18: src = sp.p[25]; dst = wp.bvdt; n = 1;      break;
        case 19: src = sp.p[12]; dst = wp.wihd; n = 1028;   break;
        case 20: src = sp.p[13]; dst = wp.whhd; n = 4;      break;
        case 21: src = sp.p[14]; dst = wp.bihd; n = 4;      break;
        case 22: src = sp.p[15]; dst = wp.bhhd; n = 4;      break;
        default: return;
    }
    for (long i = threadIdx.x; i < n; i += 256) {
        float v = bf ? bs2f(((const ushort_t*)src)[i]) : ((const float*)src)[i];
        dst[i] = f2bs(v);
    }
}

// ---------------------------------------------------------------------------
// k_permA: y=0: Whh (1024x256 row-major) -> fragment-major (encoder layout).
//          y=1: Wih -> PLAIN bf16 copy (row-major; consumed by the AX GEMM).
// ---------------------------------------------------------------------------
__global__ __launch_bounds__(256) void k_permA(
    const void* whh_src, const void* wih_src,
    ushort_t* whhp, ushort_t* wihb, const int* flagp)
{
    int bf = *flagp;
    long base = (long)blockIdx.x * 2048;
    if (blockIdx.y == 1) {
#pragma unroll
        for (int ii = 0; ii < 8; ++ii) {
            long p = base + threadIdx.x + ii * 256;
            wihb[p] = f2bs(gload(wih_src, p, bf));
        }
        return;
    }
#pragma unroll
    for (int ii = 0; ii < 8; ++ii) {
        long p = base + threadIdx.x + ii * 256;
        int c = (int)(p >> 9), l = (int)((p >> 3) & 63), e = (int)(p & 7);
        int w = c >> 5, kk = (c >> 2) & 7, g = c & 3;
        int q = l >> 4, ln = l & 15;
        long si = (long)(g * 256 + w * 16 + ln) * 256 + kk * 32 + q * 8 + e;
        whhp[p] = f2bs(gload(whh_src, si, bf));
    }
}

// ---------------------------------------------------------------------------
// k_permB: Wes (256x512 row-major) -> fragment-major. c = w*16 + kk (kk 0..15).
// ---------------------------------------------------------------------------
__global__ __launch_bounds__(256) void k_permB(
    const void* wes_src, ushort_t* wesp, const int* flagp)
{
    int bf = *flagp;
    long base = (long)blockIdx.x * 2048;
#pragma unroll
    for (int ii = 0; ii < 8; ++ii) {
        long p = base + threadIdx.x + ii * 256;
        int c = (int)(p >> 9), l = (int)((p >> 3) & 63), e = (int)(p & 7);
        int w = c >> 4, kk = c & 15;
        int q = l >> 4, ln = l & 15;
        long si = (long)(w * 16 + ln) * 512 + kk * 32 + q * 8 + e;
        wesp[p] = f2bs(gload(wes_src, si, bf));
    }
}

// ---------------------------------------------------------------------------
// k_build: features. 24576 blocks x 256 thr, 4 rows/block.
// ---------------------------------------------------------------------------
__global__ __launch_bounds__(256) void k_build(
    const void* __restrict__ pq, const void* __restrict__ cfg_in,
    const int* __restrict__ timei, WsPtrs wp, const int* __restrict__ flagp,
    ushort_t* __restrict__ inputs)
{
    int bf = *flagp;
    int ch = threadIdx.x;
    for (int rr = 0; rr < 4; ++rr) {
        long row = (long)blockIdx.x * 4 + rr;
        float v;
        if (ch < 235) {
            v = gload(pq, row * 235 + ch, bf);
        } else if (ch < 245) {
            int j = ch - 235;
            float acc = bs2f(wp.bcfg[j]);
            for (int k = 0; k < 32; ++k)
                acc += gload(cfg_in, row * 32 + k, bf) * bs2f(wp.wcfg[j * 32 + k]);
            v = acc;
        } else if (ch < 250) {
            v = bs2f(wp.eh[timei[row * 3 + 0] * 5 + (ch - 245)]);
        } else if (ch < 253) {
            v = bs2f(wp.ew[timei[row * 3 + 1] * 3 + (ch - 250)]);
        } else {
            v = bs2f(wp.es[timei[row * 3 + 2] * 3 + (ch - 253)]);
        }
        inputs[row * 256 + ch] = f2bs(v);
    }
}

// ---------------------------------------------------------------------------
// k_gemm: out = A @ W.T (+ bias). A:(98304x256), W row-major ws bf16, K=256.
// 128x128 tiles, BK=32, 4 waves of 64x64.
// ---------------------------------------------------------------------------
__global__ __launch_bounds__(256) void k_gemm(
    const ushort_t* __restrict__ A, const ushort_t* __restrict__ W,
    const ushort_t* __restrict__ bias, ushort_t* __restrict__ out,
    int ostride, int gatherB)
{
    const int K = 256;
    __shared__ alignas(16) ushort_t At[128][40];
    __shared__ alignas(16) ushort_t Bt[128][40];

    int tid  = threadIdx.x;
    int lane = tid & 63, wave = tid >> 6;
    int wm = wave >> 1, wn = wave & 1;
    int q = lane >> 4, ln = lane & 15;
    long mbase = (long)blockIdx.x * 128;

    floatx4 acc[4][4];
#pragma unroll
    for (int i = 0; i < 4; ++i)
#pragma unroll
        for (int j = 0; j < 4; ++j) acc[i][j] = (floatx4){0.f, 0.f, 0.f, 0.f};

    for (int k0 = 0; k0 < K; k0 += 32) {
        __syncthreads();
#pragma unroll
        for (int it = 0; it < 2; ++it) {
            int c = tid + it * 256;
            int r = c >> 2, kc = (c & 3) * 8;
            int wrow = gatherB ? (((r & 3) << 8) + ((int)blockIdx.y << 5) + (r >> 2))
                               : ((int)blockIdx.y * 128 + r);
            *reinterpret_cast<short8*>(&At[r][kc]) = ld8(&A[(mbase + r) * K + k0 + kc]);
            *reinterpret_cast<short8*>(&Bt[r][kc]) = ld8(&W[(long)wrow * K + k0 + kc]);
        }
        __syncthreads();
        short8 af[4];
#pragma unroll
        for (int mt = 0; mt < 4; ++mt)
            af[mt] = *reinterpret_cast<const short8*>(&At[wm * 64 + mt * 16 + ln][q * 8]);
#pragma unroll
        for (int nt = 0; nt < 4; ++nt) {
            short8 bf = *reinterpret_cast<const short8*>(&Bt[wn * 64 + nt * 16 + ln][q * 8]);
#pragma unroll
            for (int mt = 0; mt < 4; ++mt)
                acc[mt][nt] = __builtin_amdgcn_mfma_f32_16x16x32_bf16(af[mt], bf, acc[mt][nt], 0, 0, 0);
        }
    }

#pragma unroll
    for (int mt = 0; mt < 4; ++mt)
#pragma unroll
        for (int nt = 0; nt < 4; ++nt)
#pragma unroll
            for (int reg = 0; reg < 4; ++reg) {
                long row = mbase + wm * 64 + mt * 16 + q * 4 + reg;
                int  col = (int)blockIdx.y * 128 + wn * 64 + nt * 16 + ln;
                float bv = bias ? bs2f(bias[col]) : 0.f;
                out[row * (long)ostride + col] = f2bs(acc[mt][nt][reg] + bv);
            }
}

// ---------------------------------------------------------------------------
// k_encoder: 64 blocks x 512 thr (8 waves), 16 rows/block, 1 block/CU.
// Wave w owns cols [w*32, w*32+32) as two 16-col slices s=0,1.
// Weight stream per wave per step: 96 x 1KB chunks, seq j in [0,96):
//   j<16: wes0 chunk j ; j<32: wes1 chunk j-16 ; j<64: whh0 chunk j-32 ;
//   else: whh1 chunk j-64  (slice-sequential, R16's proven order).
// 8-slot REGISTER ring Wr[8] (64 VGPRs), slot = j&7 (96%8==0: invariant),
// refilled by asm global_load_dwordx4 ("+v"), strict vmcnt(7)+sched_barrier;
// refills cross barriers and the step boundary. mid/ax/wi are plain ops
// (compiler-inserted waits; only make ring waits stricter).
// Schedule: mid(t-1)|ax/wi| attn s0,s1 (seqs 0..31)+epi | barA |
//           aval | gates+cell s0 (32..63), s1 (64..95) | barC
// ---------------------------------------------------------------------------
#define MFMA16(a, b, c) __builtin_amdgcn_mfma_f32_16x16x32_bf16((a), (b), (c), 0, 0, 0)

__global__ __launch_bounds__(512, 2) void k_encoder(
    const ushort_t* __restrict__ wi, const ushort_t* __restrict__ ax,
    WsPtrs wp, ushort_t* __restrict__ mid)
{
    __shared__ alignas(16) ushort_t hcb[2][16][520];   // 33 KB [h|c] dbuf
    __shared__ alignas(16) float aPartT[16][20];       // [wprime][row]
    __shared__ ushort_t occupancy_pad[30720];          // 60 KB: 1 block/CU

    int tid  = threadIdx.x;
    int lane = tid & 63, w = tid >> 6;                 // w in [0,8)
    int q = lane >> 4, ln = lane & 15;
    long row0 = (long)blockIdx.x * 16;
    int u0 = w * 32 + ln;

    for (int i = tid; i < 2 * 16 * 520; i += 512) ((ushort_t*)hcb)[i] = 0;

    float bc[2][4], vds[2];
#pragma unroll
    for (int s = 0; s < 2; ++s) {
        int us = u0 + s * 16;
        bc[s][0] = bs2f(wp.bih[us])       + bs2f(wp.bhh[us]);
        bc[s][1] = bs2f(wp.bih[256 + us]) + bs2f(wp.bhh[256 + us]);
        bc[s][2] = bs2f(wp.bih[512 + us]) + bs2f(wp.bhh[512 + us]);
        bc[s][3] = bs2f(wp.bih[768 + us]) + bs2f(wp.bhh[768 + us]);
        vds[s]   = bs2f(wp.vds[us]);
    }
    float bVd = bs2f(wp.bvds[0]);

    const ushort_t* wesW0 = wp.wes + ((long)(2 * w)     << 13) + lane * 8;
    const ushort_t* wesW1 = wp.wes + ((long)(2 * w + 1) << 13) + lane * 8;
    const ushort_t* whhW0 = wp.whh + ((long)(2 * w)     << 14) + lane * 8;
    const ushort_t* whhW1 = wp.whh + ((long)(2 * w + 1) << 14) + lane * 8;

    // single base pointers (per-reg offsets recomputed; saves VGPRs)
    const ushort_t* wiB0 = wi + ((row0 + q * 4) * 96) * 256 + u0;
    const ushort_t* axB0 = ax + ((row0 + q * 4) * 96) * 1024 + u0 * 4;

    int mr = tid >> 5, mc = (tid & 31) * 8;            // mid-writer: 16B each
    ushort_t* midB = mid + (row0 + mr) * 96 * 256 + mc;

    // keep the pad alive (branch never taken: gridDim.x == 64)
    if (blockIdx.x > 60000) {
        occupancy_pad[tid] = (ushort_t)tid;
        midB[0] = occupancy_pad[(tid + 1) & 511];
    }

    float creg[2][4] = {{0.f, 0.f, 0.f, 0.f}, {0.f, 0.f, 0.f, 0.f}};
    __syncthreads();

    // seq j -> global chunk address (compile-time resolved: j is unrolled)
    auto sp3 = [&](int j) -> const ushort_t* {
        if (j < 16)  return wesW0 + ((j & 15) << 9);
        if (j < 32)  return wesW1 + ((j & 15) << 9);
        if (j < 64)  return whhW0 + (((j - 32) & 31) << 9);
        return whhW1 + (((j - 64) & 31) << 9);
    };

    // ---- ring prologue: seqs 0..7 in flight
    short8 Wr[8] = {};
#pragma unroll
    for (int j = 0; j < 8; ++j) GLD16R(Wr[j], sp3(j));

    for (int t = 0; t < 96; ++t) {
        ushort_t (*R)[520]  = hcb[t & 1];
        ushort_t (*Wb)[520] = hcb[(t & 1) ^ 1];

        // ---- coalesced mid write for step t-1 (t=0: dummy to slot 95)
        {
            long toff = (long)(t > 0 ? t - 1 : 95) * 256;
            uint4 hv = *reinterpret_cast<const uint4*>(&R[mr][mc]);
            *reinterpret_cast<uint4*>(midB + toff) = hv;
        }
        // ---- ax (2x4x8B) + wi (2x4x2B) prefetch (plain; compiler-scheduled)
        short4v axv[2][4]; float wiv[2][4];
#pragma unroll
        for (int reg = 0; reg < 4; ++reg) {
            const ushort_t* a0 = axB0 + ((long)reg * 96 + t) * 1024;
            axv[0][reg] = *reinterpret_cast<const short4v*>(a0);
            axv[1][reg] = *reinterpret_cast<const short4v*>(a0 + 64);
            const ushort_t* w0 = wiB0 + ((long)reg * 96 + t) * 256;
            wiv[0][reg] = bs2f(w0[0]);
            wiv[1][reg] = bs2f(w0[16]);
        }

        // ---- attn matvec per slice: K=512 over [h|c]; seqs s*16 .. s*16+15
#pragma unroll
        for (int s = 0; s < 2; ++s) {
            floatx4 acc1 = (floatx4){0.f, 0.f, 0.f, 0.f};
#pragma unroll
            for (int c = 0; c < 16; ++c) {
                const int j = s * 16 + c;
                short8 af = ld8(&R[ln][c * 32 + q * 8]);
                VW7();
                acc1 = MFMA16(af, Wr[j & 7], acc1);
                GLD16R(Wr[j & 7], sp3((j + 8) % 96));
            }
            // epilogue: tanh, scale, reduce over 16 ln lanes
            float p4[4];
#pragma unroll
            for (int reg = 0; reg < 4; ++reg)
                p4[reg] = ftanh(acc1[reg] + wiv[s][reg]) * vds[s];
#pragma unroll
            for (int m = 1; m < 16; m <<= 1) {
#pragma unroll
                for (int reg = 0; reg < 4; ++reg)
                    p4[reg] += __shfl_xor(p4[reg], m, 64);
            }
            if (ln == 0) {
                floatx4 pv = {p4[0], p4[1], p4[2], p4[3]};
                *reinterpret_cast<floatx4*>(&aPartT[2 * w + s][q * 4]) = pv;
            }
        }
        bar_lgkm();   // barrier A: aPartT visible (ring loads stay live)

        // ---- aval: per-row sum of 16 wprime partials (broadcast b128 reads)
        floatx4 av = {bVd, bVd, bVd, bVd};
#pragma unroll
        for (int ww = 0; ww < 16; ++ww)
            av += *reinterpret_cast<const floatx4*>(&aPartT[ww][q * 4]);

        // ---- gates + cell per slice: seqs 32+s*32 .. 32+s*32+31
#pragma unroll
        for (int s = 0; s < 2; ++s) {
            floatx4 aH[4];
#pragma unroll
            for (int g = 0; g < 4; ++g) aH[g] = (floatx4){0.f, 0.f, 0.f, 0.f};
#pragma unroll
            for (int kk = 0; kk < 8; ++kk) {
                short8 af = ld8(&R[ln][kk * 32 + q * 8]);
#pragma unroll
                for (int g = 0; g < 4; ++g) {
                    const int j = 32 + s * 32 + kk * 4 + g;
                    VW7();
                    aH[g] = MFMA16(af, Wr[j & 7], aH[g]);
                    GLD16R(Wr[j & 7], sp3((j + 8) % 96));   // wraps to next step
                }
            }
            int us = u0 + s * 16;
#pragma unroll
            for (int reg = 0; reg < 4; ++reg) {
                float a  = av[reg];
                float gi = aH[0][reg] + a * bs2f((ushort_t)axv[s][reg][0]) + bc[s][0];
                float gf = aH[1][reg] + a * bs2f((ushort_t)axv[s][reg][1]) + bc[s][1];
                float gg = aH[2][reg] + a * bs2f((ushort_t)axv[s][reg][2]) + bc[s][2];
                float go = aH[3][reg] + a * bs2f((ushort_t)axv[s][reg][3]) + bc[s][3];
                float c2 = sigm(gf) * creg[s][reg] + sigm(gi) * ftanh(gg);
                float h2 = sigm(go) * ftanh(c2);
                creg[s][reg] = c2;
                int r = q * 4 + reg;
                Wb[r][us] = f2bs(h2);
                Wb[r][256 + us] = f2bs(c2);
            }
        }
        bar_lgkm();   // barrier C: new state published
    }

    // retire dangling ring loads, then the real final mid write (h_96)
    asm volatile("s_waitcnt vmcnt(0)" ::: "memory");
    {
        uint4 hv = *reinterpret_cast<const uint4*>(&hcb[0][mr][mc]);
        *reinterpret_cast<uint4*>(midB + 95L * 256) = hv;
    }
}

// ---------------------------------------------------------------------------
// k_decoder: 1024 blocks (one batch row), 256 thr, 16 sequential steps.
// ---------------------------------------------------------------------------
__global__ __launch_bounds__(256) void k_decoder(
    const ushort_t* __restrict__ mid, const ushort_t* __restrict__ wd,
    WsPtrs wp, const int* __restrict__ flagp, void* __restrict__ out)
{
    __shared__ ushort_t wdl[96][264];
    __shared__ float qL[256], aLs[96], ctxL[256], VdtL[256], gL[4];
    __shared__ float st[3];

    int tid = threadIdx.x;
    long b = blockIdx.x;
    int bf = *flagp;

    for (int c = tid; c < 96 * 256; c += 256) {
        int tp = c >> 8, chn = c & 255;
        wdl[tp][chn] = wd[(b * 96 + tp) * 256 + chn];
    }
    qL[tid] = 0.f; ctxL[tid] = 0.f;
    if (tid < 96) aLs[tid] = 0.f;
    if (tid < 4)  gL[tid] = 0.f;
    VdtL[tid] = bs2f(wp.vdt[tid]);
    if (tid == 0) {
        st[0] = 0.f; st[1] = 0.f;
        st[2] = bs2f(mid[(b * 96 + 95) * 256 + 2]);
    }
    float bVdt = bs2f(wp.bvdt[0]);
    float w2a = bs2f(wp.wd2t[tid * 2]), w2b = bs2f(wp.wd2t[tid * 2 + 1]);
    __syncthreads();

    for (int s = 0; s < 16; ++s) {
        float hi = st[0], ci = st[1], prev = st[2];
        qL[tid] = hi * w2a + ci * w2b;
        __syncthreads();
        {   // attn scores: wave v, lanes split the 256-dot
            int v = tid >> 6, l = tid & 63;
            for (int tp = v; tp < 96; tp += 4) {
                float sacc = 0.f;
#pragma unroll
                for (int e = 0; e < 4; ++e) {
                    int u = l * 4 + e;
                    sacc += ftanh(qL[u] + bs2f(wdl[tp][u])) * VdtL[u];
                }
#pragma unroll
                for (int m = 1; m < 64; m <<= 1) sacc += __shfl_xor(sacc, m, 64);
                if (l == 0) aLs[tp] = sacc + bVdt;
            }
        }
        __syncthreads();
        {
            float acc = 0.f;
            for (int tp = 0; tp < 96; ++tp)
                acc += aLs[tp] * bs2f(mid[(b * 96 + tp) * 256 + tid]);
            ctxL[tid] = acc;
        }
        __syncthreads();
        {   // gates: wave g computes gate g; lanes split the ctx-dot
            int g = tid >> 6, k = tid & 63;
            float part = 0.f;
#pragma unroll
            for (int e = 0; e < 4; ++e) {
                int u = k + e * 64;
                part += bs2f(wp.wihd[g * 257 + u]) * ctxL[u];
            }
#pragma unroll
            for (int m = 1; m < 64; m <<= 1) part += __shfl_xor(part, m, 64);
            if (k == 0)
                gL[g] = part + bs2f(wp.bihd[g]) + bs2f(wp.bhhd[g])
                      + bs2f(wp.whhd[g]) * hi + bs2f(wp.wihd[g * 257 + 256]) * prev;
        }
        __syncthreads();
        if (tid == 0) {
            float c2 = sigm(gL[1]) * ci + sigm(gL[0]) * ftanh(gL[2]);
            float h2 = sigm(gL[3]) * ftanh(c2);
            st[0] = h2; st[1] = c2; st[2] = h2;
            long oi = b * 16 + s;
            if (bf) ((ushort_t*)out)[oi] = f2bs(h2);
            else    ((float*)out)[oi] = h2;
        }
        __syncthreads();
    }
}

// ---------------------------------------------------------------------------
extern "C" void kernel_launch(void* const* d_in, const int* in_sizes, int n_in,
                              void* d_out, int out_size, void* d_ws, size_t ws_size,
                              hipStream_t stream)
{
    const long MT = 1024L * 96;   // 98304 rows

    int* flagp = (int*)d_ws;
    ushort_t* base = (ushort_t*)((char*)d_ws + 256);

    SrcPtrs sp;
    for (int i = 0; i < 26; ++i) sp.p[i] = d_in[i];

    static const long sizes[23] = {
        320, 10, 120, 24, 15, 65536, 256, 131072, 256, 1,
        262144, 262144, 1024, 1024, 65536, 256, 512, 256, 1,
        1028, 4, 4, 4
    };
    ushort_t* ptrs[23];
    long off = 0;
    for (int i = 0; i < 23; ++i) {
        ptrs[i] = base + off;
        off += (sizes[i] + 7) & ~7L;   // 16B-aligned layout
    }

    WsPtrs wp;
    wp.wcfg = ptrs[0];  wp.bcfg = ptrs[1];  wp.eh   = ptrs[2];  wp.ew   = ptrs[3];
    wp.es   = ptrs[4];  wp.wis  = ptrs[5];  wp.bis  = ptrs[6];  wp.wes  = ptrs[7];
    wp.vds  = ptrs[8];  wp.bvds = ptrs[9];  wp.whh  = ptrs[10]; wp.wih  = ptrs[11];
    wp.bih  = ptrs[12]; wp.bhh  = ptrs[13]; wp.wdt  = ptrs[14]; wp.bdt  = ptrs[15];
    wp.wd2t = ptrs[16]; wp.vdt  = ptrs[17]; wp.bvdt = ptrs[18]; wp.wihd = ptrs[19];
    wp.whhd = ptrs[20]; wp.bihd = ptrs[21]; wp.bhhd = ptrs[22];

    ushort_t* inputs = base + off;            // MT*256
    ushort_t* wib    = inputs + MT * 256;     // MT*256
    ushort_t* midb   = wib + MT * 256;        // MT*256
    ushort_t* axb    = midb + MT * 256;       // MT*1024 (201 MB): AX = x@Wih.T
    ushort_t* wdb    = wib;                   // alias: wi dead after encoder

    k_detect<<<1, 64, 0, stream>>>(d_in[3], flagp);
    k_cvt<<<23, 256, 0, stream>>>(sp, wp, flagp);
    k_permA<<<dim3(128, 2), 256, 0, stream>>>(d_in[9], d_in[8], wp.whh, wp.wih, flagp);
    k_permB<<<64, 256, 0, stream>>>(d_in[18], wp.wes, flagp);
    k_build<<<24576, 256, 0, stream>>>(d_in[0], d_in[1], (const int*)d_in[2],
                                       wp, flagp, inputs);
    k_gemm<<<dim3(768, 2), 256, 0, stream>>>(inputs, wp.wis, wp.bis, wib, 256, 0);
    k_gemm<<<dim3(768, 8), 256, 0, stream>>>(inputs, wp.wih, nullptr, axb, 1024, 1);
    k_encoder<<<64, 512, 0, stream>>>(wib, axb, wp, midb);
    k_gemm<<<dim3(768, 2), 256, 0, stream>>>(midb, wp.wdt, wp.bdt, wdb, 256, 0);
    k_decoder<<<1024, 256, 0, stream>>>(midb, wdb, wp, flagp, d_out);
}

// Round 16
// 2306.475 us; speedup vs baseline: 1.2272x; 1.0233x over previous
//
#include <hip/hip_runtime.h>
#include <hip/hip_bf16.h>

// ---------------------------------------------------------------------------
// Round 20: bank R16's encoder (proven floor) + fused A-resident GEMM.
//   R19 showed ring depth 4->8 changes nothing (VGPR stuck 128, dur +6%):
//   the encoder sits at the occupancy-limited L2->CU throughput roofline
//   (~26 B/cy -> 29.5k cy/step). Encoder reverted to EXACT R16 (1190us).
//   New k_gemmN: stages the full-K 128x256 A-tile ONCE in LDS (64KB) and
//   loops N-tiles internally -- kills the 8x A re-read of the old AX GEMM
//   (400->50MB) and the wi GEMM's extra A pass; wd GEMM gets the same
//   treatment (nax=0 mode). Two launches replace three.
// ---------------------------------------------------------------------------

typedef unsigned short ushort_t;
using short4v = __attribute__((ext_vector_type(4))) short;   // 4 x bf16
using short8  = __attribute__((ext_vector_type(8))) short;   // 8 x bf16
using floatx4 = __attribute__((ext_vector_type(4))) float;   // MFMA accumulator

#define DEVFN static __device__ __forceinline__

DEVFN float bs2f(ushort_t u) {
    union { float f; unsigned v; } c; c.v = ((unsigned)u) << 16; return c.f;
}
DEVFN ushort_t f2bs(float f) {
    __hip_bfloat16 h = __float2bfloat16(f);
    return *reinterpret_cast<ushort_t*>(&h);
}
DEVFN float gload(const void* p, long i, int bf) {
    if (bf) return bs2f(((const ushort_t*)p)[i]);
    return ((const float*)p)[i];
}
DEVFN float sigm(float x) { return 1.f / (1.f + __expf(-x)); }
DEVFN float ftanh(float x) {
    float t = __expf(-2.f * fabsf(x));
    float r = (1.f - t) / (1.f + t);
    return copysignf(r, x);
}
DEVFN short8 ld8(const ushort_t* p) { return *reinterpret_cast<const short8*>(p); }

// publish LDS writes + barrier WITHOUT draining vmcnt (ring loads stay live)
DEVFN void bar_lgkm() {
    asm volatile("s_waitcnt lgkmcnt(0)" ::: "memory");
    __builtin_amdgcn_s_barrier();
}

// ring refill: in-place register redefine. "+v" ties the new load to the same
// physical regs (no SSA balloon) and orders it after the consuming MFMA.
#define GLD16R(dst, src) \
    asm volatile("global_load_dwordx4 %0, %1, off" : "+v"(dst) : "v"(src))

// strict ring wait: at consume of seq j exactly 3 ring refills are younger;
// interleaved plain VMEM only makes the wait stricter (in-order retirement).
// sched_barrier(0x3F7) = everything-but-MFMA may cross: pins the consuming
// MFMA below the wait (rule #18) without constraining DS/VALU scheduling.
#define VW3() do { asm volatile("s_waitcnt vmcnt(3)"); \
                   __builtin_amdgcn_sched_barrier(0x3F7); } while (0)

struct SrcPtrs { const void* p[26]; };
struct WsPtrs {
    // wes/whh hold PERMUTED (fragment-major) data; wih holds PLAIN bf16
    // row-major Wih_e (GEMM input).
    ushort_t *wcfg, *bcfg, *eh, *ew, *es, *wis, *bis, *wes, *vds, *bvds,
             *whh, *wih, *bih, *bhh, *wdt, *bdt, *wd2t, *vdt, *bvdt,
             *wihd, *whhd, *bihd, *bhhd;
};

// ---------------------------------------------------------------------------
__global__ void k_detect(const void* probe, int* flag) {
    if (threadIdx.x == 0 && blockIdx.x == 0) {
        const ushort_t* u = (const ushort_t*)probe;
        int ok = 1;
        for (int i = 0; i < 16; ++i) {
            ushort_t v = u[2 * i];
            int e = (v >> 7) & 0xFF;
            if (!(v == 0 || (e >= 96 && e <= 126))) ok = 0;
        }
        *flag = ok;
    }
}

// ---------------------------------------------------------------------------
// k_cvt: small tensors only (wes/whh/wih are handled by the perm kernels).
// ---------------------------------------------------------------------------
__global__ __launch_bounds__(256) void k_cvt(SrcPtrs sp, WsPtrs wp, const int* flagp) {
    int bf = *flagp;
    const void* src = nullptr; ushort_t* dst = nullptr; long n = 0;
    switch (blockIdx.x) {
        case 0:  src = sp.p[3];  dst = wp.wcfg; n = 320;    break;
        case 1:  src = sp.p[4];  dst = wp.bcfg; n = 10;     break;
        case 2:  src = sp.p[5];  dst = wp.eh;   n = 120;    break;
        case 3:  src = sp.p[6];  dst = wp.ew;   n = 24;     break;
        case 4:  src = sp.p[7];  dst = wp.es;   n = 15;     break;
        case 5:  src = sp.p[16]; dst = wp.wis;  n = 65536;  break;
        case 6:  src = sp.p[17]; dst = wp.bis;  n = 256;    break;
        case 8:  src = sp.p[19]; dst = wp.vds;  n = 256;    break;
        case 9:  src = sp.p[20]; dst = wp.bvds; n = 1;      break;
        case 12: src = sp.p[10]; dst = wp.bih;  n = 1024;   break;
        case 13: src = sp.p[11]; dst = wp.bhh;  n = 1024;   break;
        case 14: src = sp.p[21]; dst = wp.wdt;  n = 65536;  break;
        case 15: src = sp.p[22]; dst = wp.bdt;  n = 256;    break;
        case 16: src = sp.p[23]; dst = wp.wd2t; n = 512;    break;
        case 17: src = sp.p[24]; dst = wp.vdt;  n = 256;    break;
        case 18: src = sp.p[25]; dst = wp.bvdt; n = 1;      break;
        case 19: src = sp.p[12]; dst = wp.wihd; n = 1028;   break;
        case 20: src = sp.p[13]; dst = wp.whhd; n = 4;      break;
        case 21: src = sp.p[14]; dst = wp.bihd; n = 4;      break;
        case 22: src = sp.p[15]; dst = wp.bhhd; n = 4;      break;
        default: return;
    }
    for (long i = threadIdx.x; i < n; i += 256) {
        float v = bf ? bs2f(((const ushort_t*)src)[i]) : ((const float*)src)[i];
        dst[i] = f2bs(v);
    }
}

// ---------------------------------------------------------------------------
// k_permA: y=0: Whh (1024x256 row-major) -> fragment-major (encoder layout).
//          y=1: Wih -> PLAIN bf16 copy (row-major; consumed by the AX GEMM).
// ---------------------------------------------------------------------------
__global__ __launch_bounds__(256) void k_permA(
    const void* whh_src, const void* wih_src,
    ushort_t* whhp, ushort_t* wihb, const int* flagp)
{
    int bf = *flagp;
    long base = (long)blockIdx.x * 2048;
    if (blockIdx.y == 1) {
#pragma unroll
        for (int ii = 0; ii < 8; ++ii) {
            long p = base + threadIdx.x + ii * 256;
            wihb[p] = f2bs(gload(wih_src, p, bf));
        }
        return;
    }
#pragma unroll
    for (int ii = 0; ii < 8; ++ii) {
        long p = base + threadIdx.x + ii * 256;
        int c = (int)(p >> 9), l = (int)((p >> 3) & 63), e = (int)(p & 7);
        int w = c >> 5, kk = (c >> 2) & 7, g = c & 3;
        int q = l >> 4, ln = l & 15;
        long si = (long)(g * 256 + w * 16 + ln) * 256 + kk * 32 + q * 8 + e;
        whhp[p] = f2bs(gload(whh_src, si, bf));
    }
}

// ---------------------------------------------------------------------------
// k_permB: Wes (256x512 row-major) -> fragment-major. c = w*16 + kk (kk 0..15).
// ---------------------------------------------------------------------------
__global__ __launch_bounds__(256) void k_permB(
    const void* wes_src, ushort_t* wesp, const int* flagp)
{
    int bf = *flagp;
    long base = (long)blockIdx.x * 2048;
#pragma unroll
    for (int ii = 0; ii < 8; ++ii) {
        long p = base + threadIdx.x + ii * 256;
        int c = (int)(p >> 9), l = (int)((p >> 3) & 63), e = (int)(p & 7);
        int w = c >> 4, kk = c & 15;
        int q = l >> 4, ln = l & 15;
        long si = (long)(w * 16 + ln) * 512 + kk * 32 + q * 8 + e;
        wesp[p] = f2bs(gload(wes_src, si, bf));
    }
}

// ---------------------------------------------------------------------------
// k_build: features. 24576 blocks x 256 thr, 4 rows/block.
// ---------------------------------------------------------------------------
__global__ __launch_bounds__(256) void k_build(
    const void* __restrict__ pq, const void* __restrict__ cfg_in,
    const int* __restrict__ timei, WsPtrs wp, const int* __restrict__ flagp,
    ushort_t* __restrict__ inputs)
{
    int bf = *flagp;
    int ch = threadIdx.x;
    for (int rr = 0; rr < 4; ++rr) {
        long row = (long)blockIdx.x * 4 + rr;
        float v;
        if (ch < 235) {
            v = gload(pq, row * 235 + ch, bf);
        } else if (ch < 245) {
            int j = ch - 235;
            float acc = bs2f(wp.bcfg[j]);
            for (int k = 0; k < 32; ++k)
                acc += gload(cfg_in, row * 32 + k, bf) * bs2f(wp.wcfg[j * 32 + k]);
            v = acc;
        } else if (ch < 250) {
            v = bs2f(wp.eh[timei[row * 3 + 0] * 5 + (ch - 245)]);
        } else if (ch < 253) {
            v = bs2f(wp.ew[timei[row * 3 + 1] * 3 + (ch - 250)]);
        } else {
            v = bs2f(wp.es[timei[row * 3 + 2] * 3 + (ch - 253)]);
        }
        inputs[row * 256 + ch] = f2bs(v);
    }
}

// ---------------------------------------------------------------------------
// k_gemmN: A-resident multi-N GEMM. A:(98304x256) bf16; stages the FULL-K
// 128x256 A-tile once in LDS (64KB), then loops y over N-tiles:
//   y < nax          : gather tiles (AX): W row = (r&3)*256 + y*32 + (r>>2),
//                      out = outg[row*1024 + y*128 + col], no bias
//   nax <= y < nax+ns: plain tiles: W = Ws row (y-nax)*128 + r,
//                      out = outs[row*256 + (y-nax)*128 + col] + bias
// 128x128 tiles, BK=32, 4 waves of 64x64 (proven R5 fragment mapping).
// ---------------------------------------------------------------------------
#define MFMA16(a, b, c) __builtin_amdgcn_mfma_f32_16x16x32_bf16((a), (b), (c), 0, 0, 0)

__global__ __launch_bounds__(256) void k_gemmN(
    const ushort_t* __restrict__ A, const ushort_t* __restrict__ Wg,
    const ushort_t* __restrict__ Ws, const ushort_t* __restrict__ bias,
    ushort_t* __restrict__ outg, ushort_t* __restrict__ outs,
    int nax, int ns)
{
    __shared__ alignas(16) ushort_t At[128][264];   // full-K A tile (+8 pad)
    __shared__ alignas(16) ushort_t Bt[128][40];

    int tid  = threadIdx.x;
    int lane = tid & 63, wave = tid >> 6;
    int wm = wave >> 1, wn = wave & 1;
    int q = lane >> 4, ln = lane & 15;
    long mbase = (long)blockIdx.x * 128;

    // stage the full 128x256 A tile once (coalesced 16B units)
#pragma unroll
    for (int it = 0; it < 16; ++it) {
        int idx = tid + it * 256;           // 4096 units of 16B
        int r = idx >> 5, u = idx & 31;
        *reinterpret_cast<short8*>(&At[r][u * 8]) =
            ld8(&A[(mbase + r) * 256 + u * 8]);
    }
    __syncthreads();

    const int ny = nax + ns;
    for (int y = 0; y < ny; ++y) {
        floatx4 acc[4][4];
#pragma unroll
        for (int i = 0; i < 4; ++i)
#pragma unroll
            for (int j = 0; j < 4; ++j) acc[i][j] = (floatx4){0.f, 0.f, 0.f, 0.f};

        for (int k0 = 0; k0 < 256; k0 += 32) {
            __syncthreads();   // Bt safe to overwrite (prev MFMA reads done)
#pragma unroll
            for (int it = 0; it < 2; ++it) {
                int c = tid + it * 256;
                int r = c >> 2, kc = (c & 3) * 8;
                const ushort_t* src;
                if (y < nax) {
                    int wrow = ((r & 3) << 8) + (y << 5) + (r >> 2);
                    src = &Wg[(long)wrow * 256 + k0 + kc];
                } else {
                    int wrow = ((y - nax) << 7) + r;
                    src = &Ws[(long)wrow * 256 + k0 + kc];
                }
                *reinterpret_cast<short8*>(&Bt[r][kc]) = ld8(src);
            }
            __syncthreads();
            short8 af[4];
#pragma unroll
            for (int mt = 0; mt < 4; ++mt)
                af[mt] = ld8(&At[wm * 64 + mt * 16 + ln][k0 + q * 8]);
#pragma unroll
            for (int nt = 0; nt < 4; ++nt) {
                short8 bf = ld8(&Bt[wn * 64 + nt * 16 + ln][q * 8]);
#pragma unroll
                for (int mt = 0; mt < 4; ++mt)
                    acc[mt][nt] = MFMA16(af[mt], bf, acc[mt][nt]);
            }
        }

        // epilogue for tile y
#pragma unroll
        for (int mt = 0; mt < 4; ++mt)
#pragma unroll
            for (int nt = 0; nt < 4; ++nt)
#pragma unroll
                for (int reg = 0; reg < 4; ++reg) {
                    long row = mbase + wm * 64 + mt * 16 + q * 4 + reg;
                    int  cc  = wn * 64 + nt * 16 + ln;
                    if (y < nax) {
                        int col = (y << 7) + cc;
                        outg[row * 1024L + col] = f2bs(acc[mt][nt][reg]);
                    } else {
                        int col = ((y - nax) << 7) + cc;
                        outs[row * 256L + col] =
                            f2bs(acc[mt][nt][reg] + bs2f(bias[col]));
                    }
                }
    }
}

// ---------------------------------------------------------------------------
// k_encoder: EXACT R16 (proven 1190us). 64 blocks x 512 thr (8 waves),
// 16 rows/block, 1 block/CU. Wave w owns cols [w*32,w*32+32) as two 16-col
// slices s=0,1. Weight stream: 96 x 1KB chunks/wave/step, slice-sequential
// (j<16 wes0, <32 wes1, <64 whh0, else whh1). 4-slot register ring Wr[4]
// ("+v" asm refills), strict vmcnt(3)+sched_barrier(0x3F7); refills cross
// barriers and the step boundary (96%4==0). mid/ax/wi plain (compiler waits).
// ---------------------------------------------------------------------------
__global__ __launch_bounds__(512) void k_encoder(
    const ushort_t* __restrict__ wi, const ushort_t* __restrict__ ax,
    WsPtrs wp, ushort_t* __restrict__ mid)
{
    __shared__ alignas(16) ushort_t hcb[2][16][520];   // 33 KB [h|c] dbuf
    __shared__ alignas(16) float aPartT[16][20];       // [wprime][row]
    __shared__ ushort_t occupancy_pad[30720];          // 60 KB: 1 block/CU

    int tid  = threadIdx.x;
    int lane = tid & 63, w = tid >> 6;                 // w in [0,8)
    int q = lane >> 4, ln = lane & 15;
    long row0 = (long)blockIdx.x * 16;
    int u0 = w * 32 + ln;

    for (int i = tid; i < 2 * 16 * 520; i += 512) ((ushort_t*)hcb)[i] = 0;

    float bc[2][4], vds[2];
#pragma unroll
    for (int s = 0; s < 2; ++s) {
        int us = u0 + s * 16;
        bc[s][0] = bs2f(wp.bih[us])       + bs2f(wp.bhh[us]);
        bc[s][1] = bs2f(wp.bih[256 + us]) + bs2f(wp.bhh[256 + us]);
        bc[s][2] = bs2f(wp.bih[512 + us]) + bs2f(wp.bhh[512 + us]);
        bc[s][3] = bs2f(wp.bih[768 + us]) + bs2f(wp.bhh[768 + us]);
        vds[s]   = bs2f(wp.vds[us]);
    }
    float bVd = bs2f(wp.bvds[0]);

    const ushort_t* wesW0 = wp.wes + ((long)(2 * w)     << 13) + lane * 8;
    const ushort_t* wesW1 = wp.wes + ((long)(2 * w + 1) << 13) + lane * 8;
    const ushort_t* whhW0 = wp.whh + ((long)(2 * w)     << 14) + lane * 8;
    const ushort_t* whhW1 = wp.whh + ((long)(2 * w + 1) << 14) + lane * 8;

    const ushort_t* wiB0 = wi + ((row0 + q * 4) * 96) * 256 + u0;
    const ushort_t* axB0 = ax + ((row0 + q * 4) * 96) * 1024 + u0 * 4;

    int mr = tid >> 5, mc = (tid & 31) * 8;            // mid-writer: 16B each
    ushort_t* midB = mid + (row0 + mr) * 96 * 256 + mc;

    // keep the pad alive (branch never taken: gridDim.x == 64)
    if (blockIdx.x > 60000) {
        occupancy_pad[tid] = (ushort_t)tid;
        midB[0] = occupancy_pad[(tid + 1) & 511];
    }

    float creg[2][4] = {{0.f, 0.f, 0.f, 0.f}, {0.f, 0.f, 0.f, 0.f}};
    __syncthreads();

    // seq j -> global chunk address (compile-time resolved: j is unrolled)
    auto sp3 = [&](int j) -> const ushort_t* {
        if (j < 16)  return wesW0 + ((j & 15) << 9);
        if (j < 32)  return wesW1 + ((j & 15) << 9);
        if (j < 64)  return whhW0 + (((j - 32) & 31) << 9);
        return whhW1 + (((j - 64) & 31) << 9);
    };

    // ---- ring prologue: seqs 0..3 in flight
    short8 Wr[4] = {};
#pragma unroll
    for (int j = 0; j < 4; ++j) GLD16R(Wr[j], sp3(j));

    for (int t = 0; t < 96; ++t) {
        ushort_t (*R)[520]  = hcb[t & 1];
        ushort_t (*Wb)[520] = hcb[(t & 1) ^ 1];

        // ---- coalesced mid write for step t-1 (t=0: dummy to slot 95)
        {
            long toff = (long)(t > 0 ? t - 1 : 95) * 256;
            uint4 hv = *reinterpret_cast<const uint4*>(&R[mr][mc]);
            *reinterpret_cast<uint4*>(midB + toff) = hv;
        }
        // ---- ax (2x4x8B) + wi (2x4x2B) prefetch (plain; compiler-scheduled)
        short4v axv[2][4]; float wiv[2][4];
#pragma unroll
        for (int reg = 0; reg < 4; ++reg) {
            const ushort_t* a0 = axB0 + ((long)reg * 96 + t) * 1024;
            axv[0][reg] = *reinterpret_cast<const short4v*>(a0);
            axv[1][reg] = *reinterpret_cast<const short4v*>(a0 + 64);
            const ushort_t* w0 = wiB0 + ((long)reg * 96 + t) * 256;
            wiv[0][reg] = bs2f(w0[0]);
            wiv[1][reg] = bs2f(w0[16]);
        }

        // ---- attn matvec per slice: K=512 over [h|c]; seqs s*16 .. s*16+15
#pragma unroll
        for (int s = 0; s < 2; ++s) {
            floatx4 acc1 = (floatx4){0.f, 0.f, 0.f, 0.f};
#pragma unroll
            for (int c = 0; c < 16; ++c) {
                const int j = s * 16 + c;
                short8 af = ld8(&R[ln][c * 32 + q * 8]);
                VW3();
                acc1 = MFMA16(af, Wr[j & 3], acc1);
                GLD16R(Wr[j & 3], sp3((j + 4) % 96));
            }
            // epilogue: tanh, scale, reduce over 16 ln lanes
            float p4[4];
#pragma unroll
            for (int reg = 0; reg < 4; ++reg)
                p4[reg] = ftanh(acc1[reg] + wiv[s][reg]) * vds[s];
#pragma unroll
            for (int m = 1; m < 16; m <<= 1) {
#pragma unroll
                for (int reg = 0; reg < 4; ++reg)
                    p4[reg] += __shfl_xor(p4[reg], m, 64);
            }
            if (ln == 0) {
                floatx4 pv = {p4[0], p4[1], p4[2], p4[3]};
                *reinterpret_cast<floatx4*>(&aPartT[2 * w + s][q * 4]) = pv;
            }
        }
        bar_lgkm();   // barrier A: aPartT visible (ring loads stay live)

        // ---- aval: per-row sum of 16 wprime partials (broadcast b128 reads)
        floatx4 av = {bVd, bVd, bVd, bVd};
#pragma unroll
        for (int ww = 0; ww < 16; ++ww)
            av += *reinterpret_cast<const floatx4*>(&aPartT[ww][q * 4]);

        // ---- gates + cell per slice: seqs 32+s*32 .. 32+s*32+31
#pragma unroll
        for (int s = 0; s < 2; ++s) {
            floatx4 aH[4];
#pragma unroll
            for (int g = 0; g < 4; ++g) aH[g] = (floatx4){0.f, 0.f, 0.f, 0.f};
#pragma unroll
            for (int kk = 0; kk < 8; ++kk) {
                short8 af = ld8(&R[ln][kk * 32 + q * 8]);
#pragma unroll
                for (int g = 0; g < 4; ++g) {
                    const int j = 32 + s * 32 + kk * 4 + g;
                    VW3();
                    aH[g] = MFMA16(af, Wr[j & 3], aH[g]);
                    GLD16R(Wr[j & 3], sp3((j + 4) % 96));   // wraps to next step
                }
            }
            int us = u0 + s * 16;
#pragma unroll
            for (int reg = 0; reg < 4; ++reg) {
                float a  = av[reg];
                float gi = aH[0][reg] + a * bs2f((ushort_t)axv[s][reg][0]) + bc[s][0];
                float gf = aH[1][reg] + a * bs2f((ushort_t)axv[s][reg][1]) + bc[s][1];
                float gg = aH[2][reg] + a * bs2f((ushort_t)axv[s][reg][2]) + bc[s][2];
                float go = aH[3][reg] + a * bs2f((ushort_t)axv[s][reg][3]) + bc[s][3];
                float c2 = sigm(gf) * creg[s][reg] + sigm(gi) * ftanh(gg);
                float h2 = sigm(go) * ftanh(c2);
                creg[s][reg] = c2;
                int r = q * 4 + reg;
                Wb[r][us] = f2bs(h2);
                Wb[r][256 + us] = f2bs(c2);
            }
        }
        bar_lgkm();   // barrier C: new state published
    }

    // retire dangling ring loads, then the real final mid write (h_96)
    asm volatile("s_waitcnt vmcnt(0)" ::: "memory");
    {
        uint4 hv = *reinterpret_cast<const uint4*>(&hcb[0][mr][mc]);
        *reinterpret_cast<uint4*>(midB + 95L * 256) = hv;
    }
}

// ---------------------------------------------------------------------------
// k_decoder: 1024 blocks (one batch row), 256 thr, 16 sequential steps.
// ---------------------------------------------------------------------------
__global__ __launch_bounds__(256) void k_decoder(
    const ushort_t* __restrict__ mid, const ushort_t* __restrict__ wd,
    WsPtrs wp, const int* __restrict__ flagp, void* __restrict__ out)
{
    __shared__ ushort_t wdl[96][264];
    __shared__ float qL[256], aLs[96], ctxL[256], VdtL[256], gL[4];
    __shared__ float st[3];

    int tid = threadIdx.x;
    long b = blockIdx.x;
    int bf = *flagp;

    for (int c = tid; c < 96 * 256; c += 256) {
        int tp = c >> 8, chn = c & 255;
        wdl[tp][chn] = wd[(b * 96 + tp) * 256 + chn];
    }
    qL[tid] = 0.f; ctxL[tid] = 0.f;
    if (tid < 96) aLs[tid] = 0.f;
    if (tid < 4)  gL[tid] = 0.f;
    VdtL[tid] = bs2f(wp.vdt[tid]);
    if (tid == 0) {
        st[0] = 0.f; st[1] = 0.f;
        st[2] = bs2f(mid[(b * 96 + 95) * 256 + 2]);
    }
    float bVdt = bs2f(wp.bvdt[0]);
    float w2a = bs2f(wp.wd2t[tid * 2]), w2b = bs2f(wp.wd2t[tid * 2 + 1]);
    __syncthreads();

    for (int s = 0; s < 16; ++s) {
        float hi = st[0], ci = st[1], prev = st[2];
        qL[tid] = hi * w2a + ci * w2b;
        __syncthreads();
        {   // attn scores: wave v, lanes split the 256-dot
            int v = tid >> 6, l = tid & 63;
            for (int tp = v; tp < 96; tp += 4) {
                float sacc = 0.f;
#pragma unroll
                for (int e = 0; e < 4; ++e) {
                    int u = l * 4 + e;
                    sacc += ftanh(qL[u] + bs2f(wdl[tp][u])) * VdtL[u];
                }
#pragma unroll
                for (int m = 1; m < 64; m <<= 1) sacc += __shfl_xor(sacc, m, 64);
                if (l == 0) aLs[tp] = sacc + bVdt;
            }
        }
        __syncthreads();
        {
            float acc = 0.f;
            for (int tp = 0; tp < 96; ++tp)
                acc += aLs[tp] * bs2f(mid[(b * 96 + tp) * 256 + tid]);
            ctxL[tid] = acc;
        }
        __syncthreads();
        {   // gates: wave g computes gate g; lanes split the ctx-dot
            int g = tid >> 6, k = tid & 63;
            float part = 0.f;
#pragma unroll
            for (int e = 0; e < 4; ++e) {
                int u = k + e * 64;
                part += bs2f(wp.wihd[g * 257 + u]) * ctxL[u];
            }
#pragma unroll
            for (int m = 1; m < 64; m <<= 1) part += __shfl_xor(part, m, 64);
            if (k == 0)
                gL[g] = part + bs2f(wp.bihd[g]) + bs2f(wp.bhhd[g])
                      + bs2f(wp.whhd[g]) * hi + bs2f(wp.wihd[g * 257 + 256]) * prev;
        }
        __syncthreads();
        if (tid == 0) {
            float c2 = sigm(gL[1]) * ci + sigm(gL[0]) * ftanh(gL[2]);
            float h2 = sigm(gL[3]) * ftanh(c2);
            st[0] = h2; st[1] = c2; st[2] = h2;
            long oi = b * 16 + s;
            if (bf) ((ushort_t*)out)[oi] = f2bs(h2);
            else    ((float*)out)[oi] = h2;
        }
        __syncthreads();
    }
}

// ---------------------------------------------------------------------------
extern "C" void kernel_launch(void* const* d_in, const int* in_sizes, int n_in,
                              void* d_out, int out_size, void* d_ws, size_t ws_size,
                              hipStream_t stream)
{
    const long MT = 1024L * 96;   // 98304 rows

    int* flagp = (int*)d_ws;
    ushort_t* base = (ushort_t*)((char*)d_ws + 256);

    SrcPtrs sp;
    for (int i = 0; i < 26; ++i) sp.p[i] = d_in[i];

    static const long sizes[23] = {
        320, 10, 120, 24, 15, 65536, 256, 131072, 256, 1,
        262144, 262144, 1024, 1024, 65536, 256, 512, 256, 1,
        1028, 4, 4, 4
    };
    ushort_t* ptrs[23];
    long off = 0;
    for (int i = 0; i < 23; ++i) {
        ptrs[i] = base + off;
        off += (sizes[i] + 7) & ~7L;   // 16B-aligned layout
    }

    WsPtrs wp;
    wp.wcfg = ptrs[0];  wp.bcfg = ptrs[1];  wp.eh   = ptrs[2];  wp.ew   = ptrs[3];
    wp.es   = ptrs[4];  wp.wis  = ptrs[5];  wp.bis  = ptrs[6];  wp.wes  = ptrs[7];
    wp.vds  = ptrs[8];  wp.bvds = ptrs[9];  wp.whh  = ptrs[10]; wp.wih  = ptrs[11];
    wp.bih  = ptrs[12]; wp.bhh  = ptrs[13]; wp.wdt  = ptrs[14]; wp.bdt  = ptrs[15];
    wp.wd2t = ptrs[16]; wp.vdt  = ptrs[17]; wp.bvdt = ptrs[18]; wp.wihd = ptrs[19];
    wp.whhd = ptrs[20]; wp.bihd = ptrs[21]; wp.bhhd = ptrs[22];

    ushort_t* inputs = base + off;            // MT*256
    ushort_t* wib    = inputs + MT * 256;     // MT*256
    ushort_t* midb   = wib + MT * 256;        // MT*256
    ushort_t* axb    = midb + MT * 256;       // MT*1024 (201 MB): AX = x@Wih.T
    ushort_t* wdb    = wib;                   // alias: wi dead after encoder

    k_detect<<<1, 64, 0, stream>>>(d_in[3], flagp);
    k_cvt<<<23, 256, 0, stream>>>(sp, wp, flagp);
    k_permA<<<dim3(128, 2), 256, 0, stream>>>(d_in[9], d_in[8], wp.whh, wp.wih, flagp);
    k_permB<<<64, 256, 0, stream>>>(d_in[18], wp.wes, flagp);
    k_build<<<24576, 256, 0, stream>>>(d_in[0], d_in[1], (const int*)d_in[2],
                                       wp, flagp, inputs);
    // fused: AX (8 gather tiles) + wi (2 plain tiles), A staged once
    k_gemmN<<<768, 256, 0, stream>>>(inputs, wp.wih, wp.wis, wp.bis,
                                     axb, wib, 8, 2);
    k_encoder<<<64, 512, 0, stream>>>(wib, axb, wp, midb);
    // wd: 2 plain tiles, A(mid) staged once
    k_gemmN<<<768, 256, 0, stream>>>(midb, nullptr, wp.wdt, wp.bdt,
                                     nullptr, wdb, 0, 2);
    k_decoder<<<1024, 256, 0, stream>>>(midb, wdb, wp, flagp, d_out);
}

// Round 17
// 2116.548 us; speedup vs baseline: 1.3373x; 1.0897x over previous
//
#include <hip/hip_runtime.h>
#include <hip/hip_bf16.h>

// ---------------------------------------------------------------------------
// Round 21: spend the dead occupancy pad on a persistent LDS weight cache.
//   Encoder is throughput-limited on the weight stream (~26 B/cy/CU; R19's
//   depth-null killed the latency story). Only fewer bytes/CU helps.
//   Each wave pins its 12 wes0 chunks (12KB) in LDS once; streamed chunks
//   drop 96 -> 84/wave/step (-12.5% of limiting traffic). 84%4==0 keeps the
//   ring slot-invariant; cached reads are LDS (invisible to vmcnt). LDS
//   129.8KB still pins 1 block/CU. Also merged cvt/permA/permB -> k_prep.
// ---------------------------------------------------------------------------

typedef unsigned short ushort_t;
using short4v = __attribute__((ext_vector_type(4))) short;   // 4 x bf16
using short8  = __attribute__((ext_vector_type(8))) short;   // 8 x bf16
using floatx4 = __attribute__((ext_vector_type(4))) float;   // MFMA accumulator

#define DEVFN static __device__ __forceinline__

DEVFN float bs2f(ushort_t u) {
    union { float f; unsigned v; } c; c.v = ((unsigned)u) << 16; return c.f;
}
DEVFN ushort_t f2bs(float f) {
    __hip_bfloat16 h = __float2bfloat16(f);
    return *reinterpret_cast<ushort_t*>(&h);
}
DEVFN float gload(const void* p, long i, int bf) {
    if (bf) return bs2f(((const ushort_t*)p)[i]);
    return ((const float*)p)[i];
}
DEVFN float sigm(float x) { return 1.f / (1.f + __expf(-x)); }
DEVFN float ftanh(float x) {
    float t = __expf(-2.f * fabsf(x));
    float r = (1.f - t) / (1.f + t);
    return copysignf(r, x);
}
DEVFN short8 ld8(const ushort_t* p) { return *reinterpret_cast<const short8*>(p); }

// publish LDS writes + barrier WITHOUT draining vmcnt (ring loads stay live)
DEVFN void bar_lgkm() {
    asm volatile("s_waitcnt lgkmcnt(0)" ::: "memory");
    __builtin_amdgcn_s_barrier();
}

// ring refill: in-place register redefine ("+v": same physregs, ordered
// after the consuming MFMA).
#define GLD16R(dst, src) \
    asm volatile("global_load_dwordx4 %0, %1, off" : "+v"(dst) : "v"(src))

// strict ring wait: at consume of stream-seq m exactly 3 ring refills are
// younger; interleaved plain VMEM only makes the wait stricter (in-order
// retirement). sched_barrier(0x3F7) pins the consuming MFMA below the wait
// (rule #18) without constraining DS/VALU scheduling.
#define VW3() do { asm volatile("s_waitcnt vmcnt(3)"); \
                   __builtin_amdgcn_sched_barrier(0x3F7); } while (0)

struct SrcPtrs { const void* p[26]; };
struct WsPtrs {
    ushort_t *wcfg, *bcfg, *eh, *ew, *es, *wis, *bis, *wes, *vds, *bvds,
             *whh, *wih, *bih, *bhh, *wdt, *bdt, *wd2t, *vdt, *bvdt,
             *wihd, *whhd, *bihd, *bhhd;
};

// ---------------------------------------------------------------------------
__global__ void k_detect(const void* probe, int* flag) {
    if (threadIdx.x == 0 && blockIdx.x == 0) {
        const ushort_t* u = (const ushort_t*)probe;
        int ok = 1;
        for (int i = 0; i < 16; ++i) {
            ushort_t v = u[2 * i];
            int e = (v >> 7) & 0xFF;
            if (!(v == 0 || (e >= 96 && e <= 126))) ok = 0;
        }
        *flag = ok;
    }
}

// ---------------------------------------------------------------------------
// k_prep: merged cvt (blocks 0..22) + Whh perm (23..150) + Wih copy
// (151..278) + Wes perm (279..342). 343 blocks x 256 thr.
// ---------------------------------------------------------------------------
__global__ __launch_bounds__(256) void k_prep(SrcPtrs sp, WsPtrs wp, const int* flagp) {
    int bf = *flagp;
    int b = (int)blockIdx.x;

    if (b < 23) {
        const void* src = nullptr; ushort_t* dst = nullptr; long n = 0;
        switch (b) {
            case 0:  src = sp.p[3];  dst = wp.wcfg; n = 320;    break;
            case 1:  src = sp.p[4];  dst = wp.bcfg; n = 10;     break;
            case 2:  src = sp.p[5];  dst = wp.eh;   n = 120;    break;
            case 3:  src = sp.p[6];  dst = wp.ew;   n = 24;     break;
            case 4:  src = sp.p[7];  dst = wp.es;   n = 15;     break;
            case 5:  src = sp.p[16]; dst = wp.wis;  n = 65536;  break;
            case 6:  src = sp.p[17]; dst = wp.bis;  n = 256;    break;
            case 8:  src = sp.p[19]; dst = wp.vds;  n = 256;    break;
            case 9:  src = sp.p[20]; dst = wp.bvds; n = 1;      break;
            case 12: src = sp.p[10]; dst = wp.bih;  n = 1024;   break;
            case 13: src = sp.p[11]; dst = wp.bhh;  n = 1024;   break;
            case 14: src = sp.p[21]; dst = wp.wdt;  n = 65536;  break;
            case 15: src = sp.p[22]; dst = wp.bdt;  n = 256;    break;
            case 16: src = sp.p[23]; dst = wp.wd2t; n = 512;    break;
            case 17: src = sp.p[24]; dst = wp.vdt;  n = 256;    break;
            case 18: src = sp.p[25]; dst = wp.bvdt; n = 1;      break;
            case 19: src = sp.p[12]; dst = wp.wihd; n = 1028;   break;
            case 20: src = sp.p[13]; dst = wp.whhd; n = 4;      break;
            case 21: src = sp.p[14]; dst = wp.bihd; n = 4;      break;
            case 22: src = sp.p[15]; dst = wp.bhhd; n = 4;      break;
            default: return;
        }
        for (long i = threadIdx.x; i < n; i += 256) {
            float v = bf ? bs2f(((const ushort_t*)src)[i]) : ((const float*)src)[i];
            dst[i] = f2bs(v);
        }
        return;
    }
    if (b < 151) {          // Whh -> fragment-major
        long base = (long)(b - 23) * 2048;
#pragma unroll
        for (int ii = 0; ii < 8; ++ii) {
            long p = base + threadIdx.x + ii * 256;
            int c = (int)(p >> 9), l = (int)((p >> 3) & 63), e = (int)(p & 7);
            int w = c >> 5, kk = (c >> 2) & 7, g = c & 3;
            int q = l >> 4, ln = l & 15;
            long si = (long)(g * 256 + w * 16 + ln) * 256 + kk * 32 + q * 8 + e;
            wp.whh[p] = f2bs(gload(sp.p[9], si, bf));
        }
        return;
    }
    if (b < 279) {          // Wih plain bf16 copy
        long base = (long)(b - 151) * 2048;
#pragma unroll
        for (int ii = 0; ii < 8; ++ii) {
            long p = base + threadIdx.x + ii * 256;
            wp.wih[p] = f2bs(gload(sp.p[8], p, bf));
        }
        return;
    }
    {                       // Wes -> fragment-major
        long base = (long)(b - 279) * 2048;
#pragma unroll
        for (int ii = 0; ii < 8; ++ii) {
            long p = base + threadIdx.x + ii * 256;
            int c = (int)(p >> 9), l = (int)((p >> 3) & 63), e = (int)(p & 7);
            int w = c >> 4, kk = c & 15;
            int q = l >> 4, ln = l & 15;
            long si = (long)(w * 16 + ln) * 512 + kk * 32 + q * 8 + e;
            wp.wes[p] = f2bs(gload(sp.p[18], si, bf));
        }
    }
}

// ---------------------------------------------------------------------------
// k_build: features. 24576 blocks x 256 thr, 4 rows/block.
// ---------------------------------------------------------------------------
__global__ __launch_bounds__(256) void k_build(
    const void* __restrict__ pq, const void* __restrict__ cfg_in,
    const int* __restrict__ timei, WsPtrs wp, const int* __restrict__ flagp,
    ushort_t* __restrict__ inputs)
{
    int bf = *flagp;
    int ch = threadIdx.x;
    for (int rr = 0; rr < 4; ++rr) {
        long row = (long)blockIdx.x * 4 + rr;
        float v;
        if (ch < 235) {
            v = gload(pq, row * 235 + ch, bf);
        } else if (ch < 245) {
            int j = ch - 235;
            float acc = bs2f(wp.bcfg[j]);
            for (int k = 0; k < 32; ++k)
                acc += gload(cfg_in, row * 32 + k, bf) * bs2f(wp.wcfg[j * 32 + k]);
            v = acc;
        } else if (ch < 250) {
            v = bs2f(wp.eh[timei[row * 3 + 0] * 5 + (ch - 245)]);
        } else if (ch < 253) {
            v = bs2f(wp.ew[timei[row * 3 + 1] * 3 + (ch - 250)]);
        } else {
            v = bs2f(wp.es[timei[row * 3 + 2] * 3 + (ch - 253)]);
        }
        inputs[row * 256 + ch] = f2bs(v);
    }
}

// ---------------------------------------------------------------------------
// k_gemmN: A-resident multi-N GEMM (R20, proven). Stages the full-K 128x256
// A-tile once (64KB LDS), loops y over N-tiles: y<nax gather (AX), else
// plain + bias. 128x128 tiles, BK=32, 4 waves of 64x64.
// ---------------------------------------------------------------------------
#define MFMA16(a, b, c) __builtin_amdgcn_mfma_f32_16x16x32_bf16((a), (b), (c), 0, 0, 0)

__global__ __launch_bounds__(256) void k_gemmN(
    const ushort_t* __restrict__ A, const ushort_t* __restrict__ Wg,
    const ushort_t* __restrict__ Ws, const ushort_t* __restrict__ bias,
    ushort_t* __restrict__ outg, ushort_t* __restrict__ outs,
    int nax, int ns)
{
    __shared__ alignas(16) ushort_t At[128][264];   // full-K A tile (+8 pad)
    __shared__ alignas(16) ushort_t Bt[128][40];

    int tid  = threadIdx.x;
    int lane = tid & 63, wave = tid >> 6;
    int wm = wave >> 1, wn = wave & 1;
    int q = lane >> 4, ln = lane & 15;
    long mbase = (long)blockIdx.x * 128;

#pragma unroll
    for (int it = 0; it < 16; ++it) {
        int idx = tid + it * 256;           // 4096 units of 16B
        int r = idx >> 5, u = idx & 31;
        *reinterpret_cast<short8*>(&At[r][u * 8]) =
            ld8(&A[(mbase + r) * 256 + u * 8]);
    }
    __syncthreads();

    const int ny = nax + ns;
    for (int y = 0; y < ny; ++y) {
        floatx4 acc[4][4];
#pragma unroll
        for (int i = 0; i < 4; ++i)
#pragma unroll
            for (int j = 0; j < 4; ++j) acc[i][j] = (floatx4){0.f, 0.f, 0.f, 0.f};

        for (int k0 = 0; k0 < 256; k0 += 32) {
            __syncthreads();
#pragma unroll
            for (int it = 0; it < 2; ++it) {
                int c = tid + it * 256;
                int r = c >> 2, kc = (c & 3) * 8;
                const ushort_t* src;
                if (y < nax) {
                    int wrow = ((r & 3) << 8) + (y << 5) + (r >> 2);
                    src = &Wg[(long)wrow * 256 + k0 + kc];
                } else {
                    int wrow = ((y - nax) << 7) + r;
                    src = &Ws[(long)wrow * 256 + k0 + kc];
                }
                *reinterpret_cast<short8*>(&Bt[r][kc]) = ld8(src);
            }
            __syncthreads();
            short8 af[4];
#pragma unroll
            for (int mt = 0; mt < 4; ++mt)
                af[mt] = ld8(&At[wm * 64 + mt * 16 + ln][k0 + q * 8]);
#pragma unroll
            for (int nt = 0; nt < 4; ++nt) {
                short8 bf = ld8(&Bt[wn * 64 + nt * 16 + ln][q * 8]);
#pragma unroll
                for (int mt = 0; mt < 4; ++mt)
                    acc[mt][nt] = MFMA16(af[mt], bf, acc[mt][nt]);
            }
        }

#pragma unroll
        for (int mt = 0; mt < 4; ++mt)
#pragma unroll
            for (int nt = 0; nt < 4; ++nt)
#pragma unroll
                for (int reg = 0; reg < 4; ++reg) {
                    long row = mbase + wm * 64 + mt * 16 + q * 4 + reg;
                    int  cc  = wn * 64 + nt * 16 + ln;
                    if (y < nax) {
                        int col = (y << 7) + cc;
                        outg[row * 1024L + col] = f2bs(acc[mt][nt][reg]);
                    } else {
                        int col = ((y - nax) << 7) + cc;
                        outs[row * 256L + col] =
                            f2bs(acc[mt][nt][reg] + bs2f(bias[col]));
                    }
                }
    }
}

// ---------------------------------------------------------------------------
// k_encoder: R16 structure + 96KB persistent LDS weight cache.
// 64 blocks x 512 thr (8 waves), 16 rows/block, 1 block/CU (LDS 129.8KB).
// Wave w owns cols [w*32,w*32+32) as two 16-col slices s=0,1.
// wes0 chunks 0..11 cached in LDS (per-wave, filled once). Streamed chunks:
// m in [0,84): m<4 -> wes0 chunk m+12 ; m<20 -> wes1 chunk m-4 ;
// m<52 -> whh0 chunk m-20 ; else whh1 chunk m-52.  84%4==0 -> ring slots
// step-invariant. 4-slot register ring Wr[4] ("+v" asm refills), strict
// vmcnt(3)+sched_barrier(0x3F7); refills cross barriers and step boundary.
// ---------------------------------------------------------------------------
__global__ __launch_bounds__(512) void k_encoder(
    const ushort_t* __restrict__ wi, const ushort_t* __restrict__ ax,
    WsPtrs wp, ushort_t* __restrict__ mid)
{
    __shared__ ushort_t wcache[8][12][512];            // 96 KB pinned weights
    __shared__ alignas(16) ushort_t hcb[2][16][520];   // 32.5 KB [h|c] dbuf
    __shared__ alignas(16) float aPartT[16][20];       // [wprime][row]

    int tid  = threadIdx.x;
    int lane = tid & 63, w = tid >> 6;                 // w in [0,8)
    int q = lane >> 4, ln = lane & 15;
    long row0 = (long)blockIdx.x * 16;
    int u0 = w * 32 + ln;

    for (int i = tid; i < 2 * 16 * 520; i += 512) ((ushort_t*)hcb)[i] = 0;

    float bc[2][4], vds[2];
#pragma unroll
    for (int s = 0; s < 2; ++s) {
        int us = u0 + s * 16;
        bc[s][0] = bs2f(wp.bih[us])       + bs2f(wp.bhh[us]);
        bc[s][1] = bs2f(wp.bih[256 + us]) + bs2f(wp.bhh[256 + us]);
        bc[s][2] = bs2f(wp.bih[512 + us]) + bs2f(wp.bhh[512 + us]);
        bc[s][3] = bs2f(wp.bih[768 + us]) + bs2f(wp.bhh[768 + us]);
        vds[s]   = bs2f(wp.vds[us]);
    }
    float bVd = bs2f(wp.bvds[0]);

    const ushort_t* wesW0 = wp.wes + ((long)(2 * w)     << 13) + lane * 8;
    const ushort_t* wesW1 = wp.wes + ((long)(2 * w + 1) << 13) + lane * 8;
    const ushort_t* whhW0 = wp.whh + ((long)(2 * w)     << 14) + lane * 8;
    const ushort_t* whhW1 = wp.whh + ((long)(2 * w + 1) << 14) + lane * 8;

    const ushort_t* wiB0 = wi + ((row0 + q * 4) * 96) * 256 + u0;
    const ushort_t* axB0 = ax + ((row0 + q * 4) * 96) * 1024 + u0 * 4;

    int mr = tid >> 5, mc = (tid & 31) * 8;            // mid-writer: 16B each
    ushort_t* midB = mid + (row0 + mr) * 96 * 256 + mc;

    // ---- fill the persistent weight cache (wave-local; no cross-wave use)
#pragma unroll
    for (int c = 0; c < 12; ++c)
        *reinterpret_cast<short8*>(&wcache[w][c][lane * 8]) = ld8(wesW0 + (c << 9));

    float creg[2][4] = {{0.f, 0.f, 0.f, 0.f}, {0.f, 0.f, 0.f, 0.f}};
    __syncthreads();   // drains vmcnt+lgkm: cache and hcb ready, counts clean

    // streamed seq m -> global chunk address (compile-time resolved)
    auto sp3m = [&](int m) -> const ushort_t* {
        if (m < 4)   return wesW0 + ((m + 12) << 9);
        if (m < 20)  return wesW1 + ((m - 4) << 9);
        if (m < 52)  return whhW0 + ((m - 20) << 9);
        return whhW1 + ((m - 52) << 9);
    };

    // ---- ring prologue: streamed seqs 0..3 in flight
    short8 Wr[4] = {};
#pragma unroll
    for (int m = 0; m < 4; ++m) GLD16R(Wr[m], sp3m(m));

    for (int t = 0; t < 96; ++t) {
        ushort_t (*R)[520]  = hcb[t & 1];
        ushort_t (*Wb)[520] = hcb[(t & 1) ^ 1];

        // ---- coalesced mid write for step t-1 (t=0: dummy to slot 95)
        {
            long toff = (long)(t > 0 ? t - 1 : 95) * 256;
            uint4 hv = *reinterpret_cast<const uint4*>(&R[mr][mc]);
            *reinterpret_cast<uint4*>(midB + toff) = hv;
        }
        // ---- ax (2x4x8B) + wi (2x4x2B) prefetch (plain; compiler-scheduled)
        short4v axv[2][4]; float wiv[2][4];
#pragma unroll
        for (int reg = 0; reg < 4; ++reg) {
            const ushort_t* a0 = axB0 + ((long)reg * 96 + t) * 1024;
            axv[0][reg] = *reinterpret_cast<const short4v*>(a0);
            axv[1][reg] = *reinterpret_cast<const short4v*>(a0 + 64);
            const ushort_t* w0 = wiB0 + ((long)reg * 96 + t) * 256;
            wiv[0][reg] = bs2f(w0[0]);
            wiv[1][reg] = bs2f(w0[16]);
        }

        // ---- attn matvec per slice: K=512 over [h|c]
        // s=0: chunks 0..11 cached (LDS), 12..15 streamed (m=0..3)
        // s=1: all streamed (m=4..19)
#pragma unroll
        for (int s = 0; s < 2; ++s) {
            floatx4 acc1 = (floatx4){0.f, 0.f, 0.f, 0.f};
#pragma unroll
            for (int c = 0; c < 16; ++c) {
                short8 af = ld8(&R[ln][c * 32 + q * 8]);
                if (s == 0 && c < 12) {
                    short8 bw = ld8(&wcache[w][c][lane * 8]);
                    acc1 = MFMA16(af, bw, acc1);
                } else {
                    const int m = (s == 0) ? (c - 12) : (c + 4);
                    VW3();
                    acc1 = MFMA16(af, Wr[m & 3], acc1);
                    GLD16R(Wr[m & 3], sp3m((m + 4) % 84));
                }
            }
            // epilogue: tanh, scale, reduce over 16 ln lanes
            float p4[4];
#pragma unroll
            for (int reg = 0; reg < 4; ++reg)
                p4[reg] = ftanh(acc1[reg] + wiv[s][reg]) * vds[s];
#pragma unroll
            for (int m = 1; m < 16; m <<= 1) {
#pragma unroll
                for (int reg = 0; reg < 4; ++reg)
                    p4[reg] += __shfl_xor(p4[reg], m, 64);
            }
            if (ln == 0) {
                floatx4 pv = {p4[0], p4[1], p4[2], p4[3]};
                *reinterpret_cast<floatx4*>(&aPartT[2 * w + s][q * 4]) = pv;
            }
        }
        bar_lgkm();   // barrier A: aPartT visible (ring loads stay live)

        // ---- aval: per-row sum of 16 wprime partials (broadcast b128 reads)
        floatx4 av = {bVd, bVd, bVd, bVd};
#pragma unroll
        for (int ww = 0; ww < 16; ++ww)
            av += *reinterpret_cast<const floatx4*>(&aPartT[ww][q * 4]);

        // ---- gates + cell per slice: streamed m = 20+s*32+kk*4+g
#pragma unroll
        for (int s = 0; s < 2; ++s) {
            floatx4 aH[4];
#pragma unroll
            for (int g = 0; g < 4; ++g) aH[g] = (floatx4){0.f, 0.f, 0.f, 0.f};
#pragma unroll
            for (int kk = 0; kk < 8; ++kk) {
                short8 af = ld8(&R[ln][kk * 32 + q * 8]);
#pragma unroll
                for (int g = 0; g < 4; ++g) {
                    const int m = 20 + s * 32 + kk * 4 + g;
                    VW3();
                    aH[g] = MFMA16(af, Wr[m & 3], aH[g]);
                    GLD16R(Wr[m & 3], sp3m((m + 4) % 84));  // wraps to next step
                }
            }
            int us = u0 + s * 16;
#pragma unroll
            for (int reg = 0; reg < 4; ++reg) {
                float a  = av[reg];
                float gi = aH[0][reg] + a * bs2f((ushort_t)axv[s][reg][0]) + bc[s][0];
                float gf = aH[1][reg] + a * bs2f((ushort_t)axv[s][reg][1]) + bc[s][1];
                float gg = aH[2][reg] + a * bs2f((ushort_t)axv[s][reg][2]) + bc[s][2];
                float go = aH[3][reg] + a * bs2f((ushort_t)axv[s][reg][3]) + bc[s][3];
                float c2 = sigm(gf) * creg[s][reg] + sigm(gi) * ftanh(gg);
                float h2 = sigm(go) * ftanh(c2);
                creg[s][reg] = c2;
                int r = q * 4 + reg;
                Wb[r][us] = f2bs(h2);
                Wb[r][256 + us] = f2bs(c2);
            }
        }
        bar_lgkm();   // barrier C: new state published
    }

    // retire dangling ring loads, then the real final mid write (h_96)
    asm volatile("s_waitcnt vmcnt(0)" ::: "memory");
    {
        uint4 hv = *reinterpret_cast<const uint4*>(&hcb[0][mr][mc]);
        *reinterpret_cast<uint4*>(midB + 95L * 256) = hv;
    }
}

// ---------------------------------------------------------------------------
// k_decoder: 1024 blocks (one batch row), 256 thr, 16 sequential steps.
// ---------------------------------------------------------------------------
__global__ __launch_bounds__(256) void k_decoder(
    const ushort_t* __restrict__ mid, const ushort_t* __restrict__ wd,
    WsPtrs wp, const int* __restrict__ flagp, void* __restrict__ out)
{
    __shared__ ushort_t wdl[96][264];
    __shared__ float qL[256], aLs[96], ctxL[256], VdtL[256], gL[4];
    __shared__ float st[3];

    int tid = threadIdx.x;
    long b = blockIdx.x;
    int bf = *flagp;

    for (int c = tid; c < 96 * 256; c += 256) {
        int tp = c >> 8, chn = c & 255;
        wdl[tp][chn] = wd[(b * 96 + tp) * 256 + chn];
    }
    qL[tid] = 0.f; ctxL[tid] = 0.f;
    if (tid < 96) aLs[tid] = 0.f;
    if (tid < 4)  gL[tid] = 0.f;
    VdtL[tid] = bs2f(wp.vdt[tid]);
    if (tid == 0) {
        st[0] = 0.f; st[1] = 0.f;
        st[2] = bs2f(mid[(b * 96 + 95) * 256 + 2]);
    }
    float bVdt = bs2f(wp.bvdt[0]);
    float w2a = bs2f(wp.wd2t[tid * 2]), w2b = bs2f(wp.wd2t[tid * 2 + 1]);
    __syncthreads();

    for (int s = 0; s < 16; ++s) {
        float hi = st[0], ci = st[1], prev = st[2];
        qL[tid] = hi * w2a + ci * w2b;
        __syncthreads();
        {   // attn scores: wave v, lanes split the 256-dot
            int v = tid >> 6, l = tid & 63;
            for (int tp = v; tp < 96; tp += 4) {
                float sacc = 0.f;
#pragma unroll
                for (int e = 0; e < 4; ++e) {
                    int u = l * 4 + e;
                    sacc += ftanh(qL[u] + bs2f(wdl[tp][u])) * VdtL[u];
                }
#pragma unroll
                for (int m = 1; m < 64; m <<= 1) sacc += __shfl_xor(sacc, m, 64);
                if (l == 0) aLs[tp] = sacc + bVdt;
            }
        }
        __syncthreads();
        {
            float acc = 0.f;
            for (int tp = 0; tp < 96; ++tp)
                acc += aLs[tp] * bs2f(mid[(b * 96 + tp) * 256 + tid]);
            ctxL[tid] = acc;
        }
        __syncthreads();
        {   // gates: wave g computes gate g; lanes split the ctx-dot
            int g = tid >> 6, k = tid & 63;
            float part = 0.f;
#pragma unroll
            for (int e = 0; e < 4; ++e) {
                int u = k + e * 64;
                part += bs2f(wp.wihd[g * 257 + u]) * ctxL[u];
            }
#pragma unroll
            for (int m = 1; m < 64; m <<= 1) part += __shfl_xor(part, m, 64);
            if (k == 0)
                gL[g] = part + bs2f(wp.bihd[g]) + bs2f(wp.bhhd[g])
                      + bs2f(wp.whhd[g]) * hi + bs2f(wp.wihd[g * 257 + 256]) * prev;
        }
        __syncthreads();
        if (tid == 0) {
            float c2 = sigm(gL[1]) * ci + sigm(gL[0]) * ftanh(gL[2]);
            float h2 = sigm(gL[3]) * ftanh(c2);
            st[0] = h2; st[1] = c2; st[2] = h2;
            long oi = b * 16 + s;
            if (bf) ((ushort_t*)out)[oi] = f2bs(h2);
            else    ((float*)out)[oi] = h2;
        }
        __syncthreads();
    }
}

// ---------------------------------------------------------------------------
extern "C" void kernel_launch(void* const* d_in, const int* in_sizes, int n_in,
                              void* d_out, int out_size, void* d_ws, size_t ws_size,
                              hipStream_t stream)
{
    const long MT = 1024L * 96;   // 98304 rows

    int* flagp = (int*)d_ws;
    ushort_t* base = (ushort_t*)((char*)d_ws + 256);

    SrcPtrs sp;
    for (int i = 0; i < 26; ++i) sp.p[i] = d_in[i];

    static const long sizes[23] = {
        320, 10, 120, 24, 15, 65536, 256, 131072, 256, 1,
        262144, 262144, 1024, 1024, 65536, 256, 512, 256, 1,
        1028, 4, 4, 4
    };
    ushort_t* ptrs[23];
    long off = 0;
    for (int i = 0; i < 23; ++i) {
        ptrs[i] = base + off;
        off += (sizes[i] + 7) & ~7L;   // 16B-aligned layout
    }

    WsPtrs wp;
    wp.wcfg = ptrs[0];  wp.bcfg = ptrs[1];  wp.eh   = ptrs[2];  wp.ew   = ptrs[3];
    wp.es   = ptrs[4];  wp.wis  = ptrs[5];  wp.bis  = ptrs[6];  wp.wes  = ptrs[7];
    wp.vds  = ptrs[8];  wp.bvds = ptrs[9];  wp.whh  = ptrs[10]; wp.wih  = ptrs[11];
    wp.bih  = ptrs[12]; wp.bhh  = ptrs[13]; wp.wdt  = ptrs[14]; wp.bdt  = ptrs[15];
    wp.wd2t = ptrs[16]; wp.vdt  = ptrs[17]; wp.bvdt = ptrs[18]; wp.wihd = ptrs[19];
    wp.whhd = ptrs[20]; wp.bihd = ptrs[21]; wp.bhhd = ptrs[22];

    ushort_t* inputs = base + off;            // MT*256
    ushort_t* wib    = inputs + MT * 256;     // MT*256
    ushort_t* midb   = wib + MT * 256;        // MT*256
    ushort_t* axb    = midb + MT * 256;       // MT*1024 (201 MB): AX = x@Wih.T
    ushort_t* wdb    = wib;                   // alias: wi dead after encoder

    k_detect<<<1, 64, 0, stream>>>(d_in[3], flagp);
    k_prep<<<343, 256, 0, stream>>>(sp, wp, flagp);
    k_build<<<24576, 256, 0, stream>>>(d_in[0], d_in[1], (const int*)d_in[2],
                                       wp, flagp, inputs);
    // fused: AX (8 gather tiles) + wi (2 plain tiles), A staged once
    k_gemmN<<<768, 256, 0, stream>>>(inputs, wp.wih, wp.wis, wp.bis,
                                     axb, wib, 8, 2);
    k_encoder<<<64, 512, 0, stream>>>(wib, axb, wp, midb);
    // wd: 2 plain tiles, A(mid) staged once
    k_gemmN<<<768, 256, 0, stream>>>(midb, nullptr, wp.wdt, wp.bdt,
                                     nullptr, wdb, 0, 2);
    k_decoder<<<1024, 256, 0, stream>>>(midb, wdb, wp, flagp, d_out);
}

// Round 19
// 2103.513 us; speedup vs baseline: 1.3456x; 1.0062x over previous
//
#include <hip/hip_runtime.h>
#include <hip/hip_bf16.h>

// ---------------------------------------------------------------------------
// Round 23: R21 verbatim (proven 2116us, absmax 2.197e-3) + decoder staging
// vectorization (numerics-identical: pure 16B copies, same consume order).
//   R22's build-fusion pushed absmax over threshold (ulp shifts in the
//   feature path amplified by the 96-step recurrence) -> the encoder-feeding
//   path (prep/build/gemm1) is FROZEN from here on. Decoder-local edits are
//   safe (no recurrence amplification to the output).
// ---------------------------------------------------------------------------

typedef unsigned short ushort_t;
using short4v = __attribute__((ext_vector_type(4))) short;   // 4 x bf16
using short8  = __attribute__((ext_vector_type(8))) short;   // 8 x bf16
using floatx4 = __attribute__((ext_vector_type(4))) float;   // MFMA accumulator

#define DEVFN static __device__ __forceinline__

DEVFN float bs2f(ushort_t u) {
    union { float f; unsigned v; } c; c.v = ((unsigned)u) << 16; return c.f;
}
DEVFN ushort_t f2bs(float f) {
    __hip_bfloat16 h = __float2bfloat16(f);
    return *reinterpret_cast<ushort_t*>(&h);
}
DEVFN float gload(const void* p, long i, int bf) {
    if (bf) return bs2f(((const ushort_t*)p)[i]);
    return ((const float*)p)[i];
}
DEVFN float sigm(float x) { return 1.f / (1.f + __expf(-x)); }
DEVFN float ftanh(float x) {
    float t = __expf(-2.f * fabsf(x));
    float r = (1.f - t) / (1.f + t);
    return copysignf(r, x);
}
DEVFN short8 ld8(const ushort_t* p) { return *reinterpret_cast<const short8*>(p); }

// publish LDS writes + barrier WITHOUT draining vmcnt (ring loads stay live)
DEVFN void bar_lgkm() {
    asm volatile("s_waitcnt lgkmcnt(0)" ::: "memory");
    __builtin_amdgcn_s_barrier();
}

// ring refill: in-place register redefine ("+v": same physregs, ordered
// after the consuming MFMA).
#define GLD16R(dst, src) \
    asm volatile("global_load_dwordx4 %0, %1, off" : "+v"(dst) : "v"(src))

// strict ring wait: at consume of stream-seq m exactly 3 ring refills are
// younger; interleaved plain VMEM only makes the wait stricter (in-order
// retirement). sched_barrier(0x3F7) pins the consuming MFMA below the wait
// (rule #18) without constraining DS/VALU scheduling.
#define VW3() do { asm volatile("s_waitcnt vmcnt(3)"); \
                   __builtin_amdgcn_sched_barrier(0x3F7); } while (0)

struct SrcPtrs { const void* p[26]; };
struct WsPtrs {
    ushort_t *wcfg, *bcfg, *eh, *ew, *es, *wis, *bis, *wes, *vds, *bvds,
             *whh, *wih, *bih, *bhh, *wdt, *bdt, *wd2t, *vdt, *bvdt,
             *wihd, *whhd, *bihd, *bhhd;
};

// ---------------------------------------------------------------------------
__global__ void k_detect(const void* probe, int* flag) {
    if (threadIdx.x == 0 && blockIdx.x == 0) {
        const ushort_t* u = (const ushort_t*)probe;
        int ok = 1;
        for (int i = 0; i < 16; ++i) {
            ushort_t v = u[2 * i];
            int e = (v >> 7) & 0xFF;
            if (!(v == 0 || (e >= 96 && e <= 126))) ok = 0;
        }
        *flag = ok;
    }
}

// ---------------------------------------------------------------------------
// k_prep: merged cvt (blocks 0..22) + Whh perm (23..150) + Wih copy
// (151..278) + Wes perm (279..342). 343 blocks x 256 thr.
// ---------------------------------------------------------------------------
__global__ __launch_bounds__(256) void k_prep(SrcPtrs sp, WsPtrs wp, const int* flagp) {
    int bf = *flagp;
    int b = (int)blockIdx.x;

    if (b < 23) {
        const void* src = nullptr; ushort_t* dst = nullptr; long n = 0;
        switch (b) {
            case 0:  src = sp.p[3];  dst = wp.wcfg; n = 320;    break;
            case 1:  src = sp.p[4];  dst = wp.bcfg; n = 10;     break;
            case 2:  src = sp.p[5];  dst = wp.eh;   n = 120;    break;
            case 3:  src = sp.p[6];  dst = wp.ew;   n = 24;     break;
            case 4:  src = sp.p[7];  dst = wp.es;   n = 15;     break;
            case 5:  src = sp.p[16]; dst = wp.wis;  n = 65536;  break;
            case 6:  src = sp.p[17]; dst = wp.bis;  n = 256;    break;
            case 8:  src = sp.p[19]; dst = wp.vds;  n = 256;    break;
            case 9:  src = sp.p[20]; dst = wp.bvds; n = 1;      break;
            case 12: src = sp.p[10]; dst = wp.bih;  n = 1024;   break;
            case 13: src = sp.p[11]; dst = wp.bhh;  n = 1024;   break;
            case 14: src = sp.p[21]; dst = wp.wdt;  n = 65536;  break;
            case 15: src = sp.p[22]; dst = wp.bdt;  n = 256;    break;
            case 16: src = sp.p[23]; dst = wp.wd2t; n = 512;    break;
            case 17: src = sp.p[24]; dst = wp.vdt;  n = 256;    break;
            case 18: src = sp.p[25]; dst = wp.bvdt; n = 1;      break;
            case 19: src = sp.p[12]; dst = wp.wihd; n = 1028;   break;
            case 20: src = sp.p[13]; dst = wp.whhd; n = 4;      break;
            case 21: src = sp.p[14]; dst = wp.bihd; n = 4;      break;
            case 22: src = sp.p[15]; dst = wp.bhhd; n = 4;      break;
            default: return;
        }
        for (long i = threadIdx.x; i < n; i += 256) {
            float v = bf ? bs2f(((const ushort_t*)src)[i]) : ((const float*)src)[i];
            dst[i] = f2bs(v);
        }
        return;
    }
    if (b < 151) {          // Whh -> fragment-major
        long base = (long)(b - 23) * 2048;
#pragma unroll
        for (int ii = 0; ii < 8; ++ii) {
            long p = base + threadIdx.x + ii * 256;
            int c = (int)(p >> 9), l = (int)((p >> 3) & 63), e = (int)(p & 7);
            int w = c >> 5, kk = (c >> 2) & 7, g = c & 3;
            int q = l >> 4, ln = l & 15;
            long si = (long)(g * 256 + w * 16 + ln) * 256 + kk * 32 + q * 8 + e;
            wp.whh[p] = f2bs(gload(sp.p[9], si, bf));
        }
        return;
    }
    if (b < 279) {          // Wih plain bf16 copy
        long base = (long)(b - 151) * 2048;
#pragma unroll
        for (int ii = 0; ii < 8; ++ii) {
            long p = base + threadIdx.x + ii * 256;
            wp.wih[p] = f2bs(gload(sp.p[8], p, bf));
        }
        return;
    }
    {                       // Wes -> fragment-major
        long base = (long)(b - 279) * 2048;
#pragma unroll
        for (int ii = 0; ii < 8; ++ii) {
            long p = base + threadIdx.x + ii * 256;
            int c = (int)(p >> 9), l = (int)((p >> 3) & 63), e = (int)(p & 7);
            int w = c >> 4, kk = c & 15;
            int q = l >> 4, ln = l & 15;
            long si = (long)(w * 16 + ln) * 512 + kk * 32 + q * 8 + e;
            wp.wes[p] = f2bs(gload(sp.p[18], si, bf));
        }
    }
}

// ---------------------------------------------------------------------------
// k_build: features. 24576 blocks x 256 thr, 4 rows/block.  (FROZEN)
// ---------------------------------------------------------------------------
__global__ __launch_bounds__(256) void k_build(
    const void* __restrict__ pq, const void* __restrict__ cfg_in,
    const int* __restrict__ timei, WsPtrs wp, const int* __restrict__ flagp,
    ushort_t* __restrict__ inputs)
{
    int bf = *flagp;
    int ch = threadIdx.x;
    for (int rr = 0; rr < 4; ++rr) {
        long row = (long)blockIdx.x * 4 + rr;
        float v;
        if (ch < 235) {
            v = gload(pq, row * 235 + ch, bf);
        } else if (ch < 245) {
            int j = ch - 235;
            float acc = bs2f(wp.bcfg[j]);
            for (int k = 0; k < 32; ++k)
                acc += gload(cfg_in, row * 32 + k, bf) * bs2f(wp.wcfg[j * 32 + k]);
            v = acc;
        } else if (ch < 250) {
            v = bs2f(wp.eh[timei[row * 3 + 0] * 5 + (ch - 245)]);
        } else if (ch < 253) {
            v = bs2f(wp.ew[timei[row * 3 + 1] * 3 + (ch - 250)]);
        } else {
            v = bs2f(wp.es[timei[row * 3 + 2] * 3 + (ch - 253)]);
        }
        inputs[row * 256 + ch] = f2bs(v);
    }
}

// ---------------------------------------------------------------------------
// k_gemmN: A-resident multi-N GEMM (proven). Stages the full-K 128x256
// A-tile once (64KB LDS), loops y over N-tiles: y<nax gather (AX), else
// plain + bias. 128x128 tiles, BK=32, 4 waves of 64x64.  (FROZEN)
// ---------------------------------------------------------------------------
#define MFMA16(a, b, c) __builtin_amdgcn_mfma_f32_16x16x32_bf16((a), (b), (c), 0, 0, 0)

__global__ __launch_bounds__(256) void k_gemmN(
    const ushort_t* __restrict__ A, const ushort_t* __restrict__ Wg,
    const ushort_t* __restrict__ Ws, const ushort_t* __restrict__ bias,
    ushort_t* __restrict__ outg, ushort_t* __restrict__ outs,
    int nax, int ns)
{
    __shared__ alignas(16) ushort_t At[128][264];   // full-K A tile (+8 pad)
    __shared__ alignas(16) ushort_t Bt[128][40];

    int tid  = threadIdx.x;
    int lane = tid & 63, wave = tid >> 6;
    int wm = wave >> 1, wn = wave & 1;
    int q = lane >> 4, ln = lane & 15;
    long mbase = (long)blockIdx.x * 128;

#pragma unroll
    for (int it = 0; it < 16; ++it) {
        int idx = tid + it * 256;           // 4096 units of 16B
        int r = idx >> 5, u = idx & 31;
        *reinterpret_cast<short8*>(&At[r][u * 8]) =
            ld8(&A[(mbase + r) * 256 + u * 8]);
    }
    __syncthreads();

    const int ny = nax + ns;
    for (int y = 0; y < ny; ++y) {
        floatx4 acc[4][4];
#pragma unroll
        for (int i = 0; i < 4; ++i)
#pragma unroll
            for (int j = 0; j < 4; ++j) acc[i][j] = (floatx4){0.f, 0.f, 0.f, 0.f};

        for (int k0 = 0; k0 < 256; k0 += 32) {
            __syncthreads();
#pragma unroll
            for (int it = 0; it < 2; ++it) {
                int c = tid + it * 256;
                int r = c >> 2, kc = (c & 3) * 8;
                const ushort_t* src;
                if (y < nax) {
                    int wrow = ((r & 3) << 8) + (y << 5) + (r >> 2);
                    src = &Wg[(long)wrow * 256 + k0 + kc];
                } else {
                    int wrow = ((y - nax) << 7) + r;
                    src = &Ws[(long)wrow * 256 + k0 + kc];
                }
                *reinterpret_cast<short8*>(&Bt[r][kc]) = ld8(src);
            }
            __syncthreads();
            short8 af[4];
#pragma unroll
            for (int mt = 0; mt < 4; ++mt)
                af[mt] = ld8(&At[wm * 64 + mt * 16 + ln][k0 + q * 8]);
#pragma unroll
            for (int nt = 0; nt < 4; ++nt) {
                short8 bf2 = ld8(&Bt[wn * 64 + nt * 16 + ln][q * 8]);
#pragma unroll
                for (int mt = 0; mt < 4; ++mt)
                    acc[mt][nt] = MFMA16(af[mt], bf2, acc[mt][nt]);
            }
        }

#pragma unroll
        for (int mt = 0; mt < 4; ++mt)
#pragma unroll
            for (int nt = 0; nt < 4; ++nt)
#pragma unroll
                for (int reg = 0; reg < 4; ++reg) {
                    long row = mbase + wm * 64 + mt * 16 + q * 4 + reg;
                    int  cc  = wn * 64 + nt * 16 + ln;
                    if (y < nax) {
                        int col = (y << 7) + cc;
                        outg[row * 1024L + col] = f2bs(acc[mt][nt][reg]);
                    } else {
                        int col = ((y - nax) << 7) + cc;
                        outs[row * 256L + col] =
                            f2bs(acc[mt][nt][reg] + bs2f(bias[col]));
                    }
                }
    }
}

// ---------------------------------------------------------------------------
// k_encoder: EXACT R21 (1003us, FROZEN). 64 blocks x 512 thr (8 waves),
// 16 rows/blk, 1 block/CU (LDS 129.8KB). wes0 chunks 0..11 cached per wave;
// streamed m in [0,84): m<4 wes0 12..15 ; m<20 wes1 ; m<52 whh0 ; else whh1.
// 4-slot register ring Wr[4] ("+v" asm refills), strict vmcnt(3); refills
// cross barriers and the step boundary (84%4==0).
// ---------------------------------------------------------------------------
__global__ __launch_bounds__(512) void k_encoder(
    const ushort_t* __restrict__ wi, const ushort_t* __restrict__ ax,
    WsPtrs wp, ushort_t* __restrict__ mid)
{
    __shared__ ushort_t wcache[8][12][512];            // 96 KB pinned weights
    __shared__ alignas(16) ushort_t hcb[2][16][520];   // 32.5 KB [h|c] dbuf
    __shared__ alignas(16) float aPartT[16][20];       // [wprime][row]

    int tid  = threadIdx.x;
    int lane = tid & 63, w = tid >> 6;                 // w in [0,8)
    int q = lane >> 4, ln = lane & 15;
    long row0 = (long)blockIdx.x * 16;
    int u0 = w * 32 + ln;

    for (int i = tid; i < 2 * 16 * 520; i += 512) ((ushort_t*)hcb)[i] = 0;

    float bc[2][4], vds[2];
#pragma unroll
    for (int s = 0; s < 2; ++s) {
        int us = u0 + s * 16;
        bc[s][0] = bs2f(wp.bih[us])       + bs2f(wp.bhh[us]);
        bc[s][1] = bs2f(wp.bih[256 + us]) + bs2f(wp.bhh[256 + us]);
        bc[s][2] = bs2f(wp.bih[512 + us]) + bs2f(wp.bhh[512 + us]);
        bc[s][3] = bs2f(wp.bih[768 + us]) + bs2f(wp.bhh[768 + us]);
        vds[s]   = bs2f(wp.vds[us]);
    }
    float bVd = bs2f(wp.bvds[0]);

    const ushort_t* wesW0 = wp.wes + ((long)(2 * w)     << 13) + lane * 8;
    const ushort_t* wesW1 = wp.wes + ((long)(2 * w + 1) << 13) + lane * 8;
    const ushort_t* whhW0 = wp.whh + ((long)(2 * w)     << 14) + lane * 8;
    const ushort_t* whhW1 = wp.whh + ((long)(2 * w + 1) << 14) + lane * 8;

    const ushort_t* wiB0 = wi + ((row0 + q * 4) * 96) * 256 + u0;
    const ushort_t* axB0 = ax + ((row0 + q * 4) * 96) * 1024 + u0 * 4;

    int mr = tid >> 5, mc = (tid & 31) * 8;            // mid-writer: 16B each
    ushort_t* midB = mid + (row0 + mr) * 96 * 256 + mc;

    // ---- fill the persistent weight cache (wave-local; no cross-wave use)
#pragma unroll
    for (int c = 0; c < 12; ++c)
        *reinterpret_cast<short8*>(&wcache[w][c][lane * 8]) = ld8(wesW0 + (c << 9));

    float creg[2][4] = {{0.f, 0.f, 0.f, 0.f}, {0.f, 0.f, 0.f, 0.f}};
    __syncthreads();   // drains vmcnt+lgkm: cache and hcb ready, counts clean

    // streamed seq m -> global chunk address (compile-time resolved)
    auto sp3m = [&](int m) -> const ushort_t* {
        if (m < 4)   return wesW0 + ((m + 12) << 9);
        if (m < 20)  return wesW1 + ((m - 4) << 9);
        if (m < 52)  return whhW0 + ((m - 20) << 9);
        return whhW1 + ((m - 52) << 9);
    };

    // ---- ring prologue: streamed seqs 0..3 in flight
    short8 Wr[4] = {};
#pragma unroll
    for (int m = 0; m < 4; ++m) GLD16R(Wr[m], sp3m(m));

    for (int t = 0; t < 96; ++t) {
        ushort_t (*R)[520]  = hcb[t & 1];
        ushort_t (*Wb)[520] = hcb[(t & 1) ^ 1];

        // ---- coalesced mid write for step t-1 (t=0: dummy to slot 95)
        {
            long toff = (long)(t > 0 ? t - 1 : 95) * 256;
            uint4 hv = *reinterpret_cast<const uint4*>(&R[mr][mc]);
            *reinterpret_cast<uint4*>(midB + toff) = hv;
        }
        // ---- ax (2x4x8B) + wi (2x4x2B) prefetch (plain; compiler-scheduled)
        short4v axv[2][4]; float wiv[2][4];
#pragma unroll
        for (int reg = 0; reg < 4; ++reg) {
            const ushort_t* a0 = axB0 + ((long)reg * 96 + t) * 1024;
            axv[0][reg] = *reinterpret_cast<const short4v*>(a0);
            axv[1][reg] = *reinterpret_cast<const short4v*>(a0 + 64);
            const ushort_t* w0 = wiB0 + ((long)reg * 96 + t) * 256;
            wiv[0][reg] = bs2f(w0[0]);
            wiv[1][reg] = bs2f(w0[16]);
        }

        // ---- attn matvec per slice: K=512 over [h|c]
        // s=0: chunks 0..11 cached (LDS), 12..15 streamed (m=0..3)
        // s=1: all streamed (m=4..19)
#pragma unroll
        for (int s = 0; s < 2; ++s) {
            floatx4 acc1 = (floatx4){0.f, 0.f, 0.f, 0.f};
#pragma unroll
            for (int c = 0; c < 16; ++c) {
                short8 af = ld8(&R[ln][c * 32 + q * 8]);
                if (s == 0 && c < 12) {
                    short8 bw = ld8(&wcache[w][c][lane * 8]);
                    acc1 = MFMA16(af, bw, acc1);
                } else {
                    const int m = (s == 0) ? (c - 12) : (c + 4);
                    VW3();
                    acc1 = MFMA16(af, Wr[m & 3], acc1);
                    GLD16R(Wr[m & 3], sp3m((m + 4) % 84));
                }
            }
            // epilogue: tanh, scale, reduce over 16 ln lanes
            float p4[4];
#pragma unroll
            for (int reg = 0; reg < 4; ++reg)
                p4[reg] = ftanh(acc1[reg] + wiv[s][reg]) * vds[s];
#pragma unroll
            for (int m = 1; m < 16; m <<= 1) {
#pragma unroll
                for (int reg = 0; reg < 4; ++reg)
                    p4[reg] += __shfl_xor(p4[reg], m, 64);
            }
            if (ln == 0) {
                floatx4 pv = {p4[0], p4[1], p4[2], p4[3]};
                *reinterpret_cast<floatx4*>(&aPartT[2 * w + s][q * 4]) = pv;
            }
        }
        bar_lgkm();   // barrier A: aPartT visible (ring loads stay live)

        // ---- aval: per-row sum of 16 wprime partials (broadcast b128 reads)
        floatx4 av = {bVd, bVd, bVd, bVd};
#pragma unroll
        for (int ww = 0; ww < 16; ++ww)
            av += *reinterpret_cast<const floatx4*>(&aPartT[ww][q * 4]);

        // ---- gates + cell per slice: streamed m = 20+s*32+kk*4+g
#pragma unroll
        for (int s = 0; s < 2; ++s) {
            floatx4 aH[4];
#pragma unroll
            for (int g = 0; g < 4; ++g) aH[g] = (floatx4){0.f, 0.f, 0.f, 0.f};
#pragma unroll
            for (int kk = 0; kk < 8; ++kk) {
                short8 af = ld8(&R[ln][kk * 32 + q * 8]);
#pragma unroll
                for (int g = 0; g < 4; ++g) {
                    const int m = 20 + s * 32 + kk * 4 + g;
                    VW3();
                    aH[g] = MFMA16(af, Wr[m & 3], aH[g]);
                    GLD16R(Wr[m & 3], sp3m((m + 4) % 84));  // wraps to next step
                }
            }
            int us = u0 + s * 16;
#pragma unroll
            for (int reg = 0; reg < 4; ++reg) {
                float a  = av[reg];
                float gi = aH[0][reg] + a * bs2f((ushort_t)axv[s][reg][0]) + bc[s][0];
                float gf = aH[1][reg] + a * bs2f((ushort_t)axv[s][reg][1]) + bc[s][1];
                float gg = aH[2][reg] + a * bs2f((ushort_t)axv[s][reg][2]) + bc[s][2];
                float go = aH[3][reg] + a * bs2f((ushort_t)axv[s][reg][3]) + bc[s][3];
                float c2 = sigm(gf) * creg[s][reg] + sigm(gi) * ftanh(gg);
                float h2 = sigm(go) * ftanh(c2);
                creg[s][reg] = c2;
                int r = q * 4 + reg;
                Wb[r][us] = f2bs(h2);
                Wb[r][256 + us] = f2bs(c2);
            }
        }
        bar_lgkm();   // barrier C: new state published
    }

    // retire dangling ring loads, then the real final mid write (h_96)
    asm volatile("s_waitcnt vmcnt(0)" ::: "memory");
    {
        uint4 hv = *reinterpret_cast<const uint4*>(&hcb[0][mr][mc]);
        *reinterpret_cast<uint4*>(midB + 95L * 256) = hv;
    }
}

// ---------------------------------------------------------------------------
// k_decoder: 1024 blocks (one batch row), 256 thr, 16 sequential steps.
// ONLY change vs R21: wd staging vectorized to 16B copies (12 iters instead
// of 96 scalar iters; bit-identical values, same consumption order).
// ---------------------------------------------------------------------------
__global__ __launch_bounds__(256) void k_decoder(
    const ushort_t* __restrict__ mid, const ushort_t* __restrict__ wd,
    WsPtrs wp, const int* __restrict__ flagp, void* __restrict__ out)
{
    __shared__ alignas(16) ushort_t wdl[96][264];
    __shared__ float qL[256], aLs[96], ctxL[256], VdtL[256], gL[4];
    __shared__ float st[3];

    int tid = threadIdx.x;
    long b = blockIdx.x;
    int bf = *flagp;

    // vectorized staging: 96 rows x 32 units of 16B = 3072 units
    for (int c = tid; c < 96 * 32; c += 256) {
        int tp = c >> 5, u8 = (c & 31) * 8;
        *reinterpret_cast<short8*>(&wdl[tp][u8]) =
            ld8(&wd[(b * 96 + tp) * 256 + u8]);
    }
    qL[tid] = 0.f; ctxL[tid] = 0.f;
    if (tid < 96) aLs[tid] = 0.f;
    if (tid < 4)  gL[tid] = 0.f;
    VdtL[tid] = bs2f(wp.vdt[tid]);
    if (tid == 0) {
        st[0] = 0.f; st[1] = 0.f;
        st[2] = bs2f(mid[(b * 96 + 95) * 256 + 2]);
    }
    float bVdt = bs2f(wp.bvdt[0]);
    float w2a = bs2f(wp.wd2t[tid * 2]), w2b = bs2f(wp.wd2t[tid * 2 + 1]);
    __syncthreads();

    for (int s = 0; s < 16; ++s) {
        float hi = st[0], ci = st[1], prev = st[2];
        qL[tid] = hi * w2a + ci * w2b;
        __syncthreads();
        {   // attn scores: wave v, lanes split the 256-dot
            int v = tid >> 6, l = tid & 63;
            for (int tp = v; tp < 96; tp += 4) {
                float sacc = 0.f;
#pragma unroll
                for (int e = 0; e < 4; ++e) {
                    int u = l * 4 + e;
                    sacc += ftanh(qL[u] + bs2f(wdl[tp][u])) * VdtL[u];
                }
#pragma unroll
                for (int m = 1; m < 64; m <<= 1) sacc += __shfl_xor(sacc, m, 64);
                if (l == 0) aLs[tp] = sacc + bVdt;
            }
        }
        __syncthreads();
        {
            float acc = 0.f;
            for (int tp = 0; tp < 96; ++tp)
                acc += aLs[tp] * bs2f(mid[(b * 96 + tp) * 256 + tid]);
            ctxL[tid] = acc;
        }
        __syncthreads();
        {   // gates: wave g computes gate g; lanes split the ctx-dot
            int g = tid >> 6, k = tid & 63;
            float part = 0.f;
#pragma unroll
            for (int e = 0; e < 4; ++e) {
                int u = k + e * 64;
                part += bs2f(wp.wihd[g * 257 + u]) * ctxL[u];
            }
#pragma unroll
            for (int m = 1; m < 64; m <<= 1) part += __shfl_xor(part, m, 64);
            if (k == 0)
                gL[g] = part + bs2f(wp.bihd[g]) + bs2f(wp.bhhd[g])
                      + bs2f(wp.whhd[g]) * hi + bs2f(wp.wihd[g * 257 + 256]) * prev;
        }
        __syncthreads();
        if (tid == 0) {
            float c2 = sigm(gL[1]) * ci + sigm(gL[0]) * ftanh(gL[2]);
            float h2 = sigm(gL[3]) * ftanh(c2);
            st[0] = h2; st[1] = c2; st[2] = h2;
            long oi = b * 16 + s;
            if (bf) ((ushort_t*)out)[oi] = f2bs(h2);
            else    ((float*)out)[oi] = h2;
        }
        __syncthreads();
    }
}

// ---------------------------------------------------------------------------
extern "C" void kernel_launch(void* const* d_in, const int* in_sizes, int n_in,
                              void* d_out, int out_size, void* d_ws, size_t ws_size,
                              hipStream_t stream)
{
    const long MT = 1024L * 96;   // 98304 rows

    int* flagp = (int*)d_ws;
    ushort_t* base = (ushort_t*)((char*)d_ws + 256);

    SrcPtrs sp;
    for (int i = 0; i < 26; ++i) sp.p[i] = d_in[i];

    static const long sizes[23] = {
        320, 10, 120, 24, 15, 65536, 256, 131072, 256, 1,
        262144, 262144, 1024, 1024, 65536, 256, 512, 256, 1,
        1028, 4, 4, 4
    };
    ushort_t* ptrs[23];
    long off = 0;
    for (int i = 0; i < 23; ++i) {
        ptrs[i] = base + off;
        off += (sizes[i] + 7) & ~7L;   // 16B-aligned layout
    }

    WsPtrs wp;
    wp.wcfg = ptrs[0];  wp.bcfg = ptrs[1];  wp.eh   = ptrs[2];  wp.ew   = ptrs[3];
    wp.es   = ptrs[4];  wp.wis  = ptrs[5];  wp.bis  = ptrs[6];  wp.wes  = ptrs[7];
    wp.vds  = ptrs[8];  wp.bvds = ptrs[9];  wp.whh  = ptrs[10]; wp.wih  = ptrs[11];
    wp.bih  = ptrs[12]; wp.bhh  = ptrs[13]; wp.wdt  = ptrs[14]; wp.bdt  = ptrs[15];
    wp.wd2t = ptrs[16]; wp.vdt  = ptrs[17]; wp.bvdt = ptrs[18]; wp.wihd = ptrs[19];
    wp.whhd = ptrs[20]; wp.bihd = ptrs[21]; wp.bhhd = ptrs[22];

    ushort_t* inputs = base + off;            // MT*256
    ushort_t* wib    = inputs + MT * 256;     // MT*256
    ushort_t* midb   = wib + MT * 256;        // MT*256
    ushort_t* axb    = midb + MT * 256;       // MT*1024 (201 MB): AX = x@Wih.T
    ushort_t* wdb    = wib;                   // alias: wi dead after encoder

    k_detect<<<1, 64, 0, stream>>>(d_in[3], flagp);
    k_prep<<<343, 256, 0, stream>>>(sp, wp, flagp);
    k_build<<<24576, 256, 0, stream>>>(d_in[0], d_in[1], (const int*)d_in[2],
                                       wp, flagp, inputs);
    // fused: AX (8 gather tiles) + wi (2 plain tiles), A staged once
    k_gemmN<<<768, 256, 0, stream>>>(inputs, wp.wih, wp.wis, wp.bis,
                                     axb, wib, 8, 2);
    k_encoder<<<64, 512, 0, stream>>>(wib, axb, wp, midb);
    // wd: 2 plain tiles, A(mid) staged once
    k_gemmN<<<768, 256, 0, stream>>>(midb, nullptr, wp.wdt, wp.bdt,
                                     nullptr, wdb, 0, 2);
    k_decoder<<<1024, 256, 0, stream>>>(midb, wdb, wp, flagp, d_out);
}